// Round 4
// baseline (12628.716 us; speedup 1.0000x reference)
//
#include <hip/hip_runtime.h>
#include <hip/hip_bf16.h>
#include <stdint.h>

using bf16 = __hip_bfloat16;
typedef __attribute__((ext_vector_type(8))) short short8;
typedef __attribute__((ext_vector_type(4))) float floatx4;

#define N_NODES  32768
#define N_EDGES  131072
#define N_GRAPH  1024
#define NPG      32
#define EPG      128
#define H_DIM    512
#define HE_DIM   128
#define OUT_DIM  1024
#define N_LAYERS 6
#define MC_ROWS  8192   // node chunk for atom MLP

__device__ __forceinline__ float b2f(bf16 v) { return __bfloat162float(v); }
__device__ __forceinline__ bf16  f2b(float f) { return __float2bfloat16(f); }
__device__ __forceinline__ floatx4 mfma16(short8 a, short8 b, floatx4 c) {
    return __builtin_amdgcn_mfma_f32_16x16x32_bf16(a, b, c, 0, 0, 0);
}
// dual-dtype load for external tensors (runtime-detected; proven bf16 but keep armor)
__device__ __forceinline__ float ldf(const void* p, size_t i, int isf) {
    return isf ? ((const float*)p)[i] : b2f(((const bf16*)p)[i]);
}
__device__ __forceinline__ short ldsh(const void* p, size_t i, int isf) {
    if (isf) { bf16 h = f2b(((const float*)p)[i]); return *(short*)&h; }
    return ((const short*)p)[i];
}

__device__ const int NODE_OFFS[9] = {0,119,128,139,151,160,165,173,175};

// ---------- dtype detection ----------
__global__ __launch_bounds__(256)
void k_detect(const unsigned short* __restrict__ tab, int n, int* __restrict__ flag)
{
    int big = 0;
    for (int i = threadIdx.x; i < n; i += 256) {
        unsigned short u = tab[i];
        int e = (u >> 7) & 0xFF;
        if (e >= 0x88) big++;
    }
    __shared__ int r[256];
    r[threadIdx.x] = big;
    __syncthreads();
    for (int s = 128; s > 0; s >>= 1) {
        if (threadIdx.x < s) r[threadIdx.x] += r[threadIdx.x + s];
        __syncthreads();
    }
    if (threadIdx.x == 0) *flag = (r[0] > 64) ? 1 : 0;
}

// ---------------- node embedding -> f32 z ----------------
__global__ __launch_bounds__(512)
void k_node_embed(const int* __restrict__ x, const void* __restrict__ tab,
                  float* __restrict__ Z, const int* __restrict__ flagp)
{
    const int isf = *flagp;
    const int n = blockIdx.x, t = threadIdx.x;
    __shared__ int xi[9];
    if (t < 9) xi[t] = NODE_OFFS[t] + x[(size_t)n * 9 + t];
    __syncthreads();
    float s = 0.f;
#pragma unroll
    for (int f = 0; f < 9; ++f) s += ldf(tab, (size_t)xi[f] * H_DIM + t, isf);
    Z[(size_t)n * H_DIM + t] = s;
}

// ------- bond BN stats from tables: mu = sum_e e, S = e^T e (e = bf16-rounded) -------
__global__ __launch_bounds__(256)
void k_bond_stats(const int* __restrict__ ea, const void* __restrict__ etab,
                  float* __restrict__ S, float* __restrict__ mu, const int* __restrict__ flagp)
{
    const int isf = *flagp;
    __shared__ float ebuf[8][128];
    const int tid = threadIdx.x;
    const int i  = tid >> 1;
    const int j0 = (tid & 1) * 64;
    float sacc[64];
#pragma unroll
    for (int t = 0; t < 64; ++t) sacc[t] = 0.f;
    float muacc = 0.f;
    const int e0 = blockIdx.x * 512;
    for (int c = 0; c < 64; ++c) {
        __syncthreads();
        {
            int el = tid >> 5, cc = (tid & 31) * 4;
            int e = e0 + c * 8 + el;
            int i0 = ea[(size_t)e * 3 + 0];
            int i1 = 119 + ea[(size_t)e * 3 + 1];
            int i2 = 128 + ea[(size_t)e * 3 + 2];
#pragma unroll
            for (int j = 0; j < 4; ++j) {
                float s = ldf(etab, (size_t)i0 * HE_DIM + cc + j, isf)
                        + ldf(etab, (size_t)i1 * HE_DIM + cc + j, isf)
                        + ldf(etab, (size_t)i2 * HE_DIM + cc + j, isf);
                ebuf[el][cc + j] = b2f(f2b(s));   // match GEMM A operand exactly
            }
        }
        __syncthreads();
#pragma unroll
        for (int e = 0; e < 8; ++e) {
            float ei = ebuf[e][i];
            if (tid < 128) muacc += ebuf[e][tid];
            const float4* row = (const float4*)(&ebuf[e][j0]);
#pragma unroll
            for (int jj = 0; jj < 16; ++jj) {
                float4 vv = row[jj];
                sacc[jj*4+0] += ei * vv.x;
                sacc[jj*4+1] += ei * vv.y;
                sacc[jj*4+2] += ei * vv.z;
                sacc[jj*4+3] += ei * vv.w;
            }
        }
    }
    float* Sp = S + (size_t)i * 128 + j0;
#pragma unroll
    for (int t = 0; t < 64; ++t) atomicAdd(Sp + t, sacc[t]);
    if (tid < 128) atomicAdd(mu + tid, muacc);
}

// ------- per-layer fold: scale1/shift1 for bond BN (bias cancels in BN) -------
__global__ __launch_bounds__(128)
void k_bond_fold(const float* __restrict__ S, const float* __restrict__ mu,
                 const void* __restrict__ bW, size_t wo,
                 const void* __restrict__ bG, const void* __restrict__ bBe, size_t go,
                 float* __restrict__ scale1, float* __restrict__ shift1,
                 const int* __restrict__ flagp)
{
    const int isf = *flagp;
    const int j = blockIdx.x;   // 0..511
    const int k = threadIdx.x;  // 0..127
    __shared__ float wbuf[128];
    __shared__ float rp[2][2];
    wbuf[k] = ldf(bW, wo + (size_t)k * H_DIM + j, isf);
    __syncthreads();
    float wk = wbuf[k];
    float dot = 0.f;
    for (int m = 0; m < 128; ++m) dot += S[(size_t)m * 128 + k] * wbuf[m];
    float p1 = wk * dot;
    float p2 = mu[k] * wk;
    for (int off = 32; off > 0; off >>= 1) {
        p1 += __shfl_down(p1, off, 64);
        p2 += __shfl_down(p2, off, 64);
    }
    if ((k & 63) == 0) { rp[k >> 6][0] = p1; rp[k >> 6][1] = p2; }
    __syncthreads();
    if (k == 0) {
        const float invE = 1.f / (float)N_EDGES;
        float wSw = rp[0][0] + rp[1][0];
        float dmu = rp[0][1] + rp[1][1];
        float mean = dmu * invE;
        float ey2  = wSw * invE;
        float var  = ey2 - mean * mean;
        var = var < 0.f ? 0.f : var;
        float rstd = rsqrtf(var + 1e-5f);
        float sc = ldf(bG, go + j, isf) * rstd;
        scale1[j] = sc;
        shift1[j] = ldf(bBe, go + j, isf) - mean * sc;
    }
}

// --- fused: e recompute; ee=relu(BN(e@bW)); msg=z[src]+ee; agg by dst; z+=agg (f32, in-place) ---
__global__ __launch_bounds__(256)
void k_bond_gemm_agg(const int* __restrict__ ea, const void* __restrict__ etab,
                     const void* __restrict__ bW, size_t wo,
                     const int* __restrict__ edge_index, const float* __restrict__ Z,
                     const float* __restrict__ scale1, const float* __restrict__ shift1,
                     float* __restrict__ X2, const int* __restrict__ flagp)
{
    const int isf = *flagp;
    const int tid = threadIdx.x;
    const int lane = tid & 63, wv = tid >> 6, q = lane >> 4, l15 = lane & 15;
    const int nc = blockIdx.x;   // col chunk (64 of 512)
    const int g  = blockIdx.y;   // graph

    __shared__ __align__(16) char smem[54784];
    bf16 (*As)[136] = (bf16(*)[136])smem;               // 128 edges x 128 K
    bf16 (*Bs)[136] = (bf16(*)[136])(smem + 34816);     // 64 cols x 128 K
    float (*Cs)[68] = (float(*)[68])smem;               // aliases As after MFMA
    int* srcl = (int*)(smem + 52224);
    int* dstl = srcl + 128;
    int (*eix)[3] = (int(*)[3])(smem + 53248);

    if (tid < 128) {
        int e = g * EPG + tid;
        srcl[tid] = edge_index[e];
        dstl[tid] = edge_index[N_EDGES + e] - g * NPG;
        eix[tid][0] = ea[(size_t)e * 3 + 0];
        eix[tid][1] = 119 + ea[(size_t)e * 3 + 1];
        eix[tid][2] = 128 + ea[(size_t)e * 3 + 2];
    }
    __syncthreads();
    {   // stage A: recompute edge embedding, 2 threads per row
        int row = tid >> 1, half = (tid & 1) * 64;
        int eb[3] = {eix[row][0], eix[row][1], eix[row][2]};
#pragma unroll
        for (int seg = 0; seg < 4; ++seg) {
            float a16[16];
#pragma unroll
            for (int j = 0; j < 16; ++j) a16[j] = 0.f;
#pragma unroll
            for (int f = 0; f < 3; ++f) {
                size_t base = (size_t)eb[f] * HE_DIM + half + seg * 16;
                if (isf) {
                    const float4* s = (const float4*)((const float*)etab + base);
#pragma unroll
                    for (int v = 0; v < 4; ++v) {
                        float4 t = s[v];
                        a16[v*4+0] += t.x; a16[v*4+1] += t.y;
                        a16[v*4+2] += t.z; a16[v*4+3] += t.w;
                    }
                } else {
                    const bf16* s = (const bf16*)etab + base;
#pragma unroll
                    for (int j = 0; j < 16; ++j) a16[j] += b2f(s[j]);
                }
            }
#pragma unroll
            for (int j = 0; j < 16; ++j) As[row][half + seg * 16 + j] = f2b(a16[j]);
        }
    }
    {   // stage B^T
        int col = tid & 63, kg = (tid >> 6) * 32;
        size_t cb = wo + (size_t)nc * 64 + col;
#pragma unroll
        for (int qq = 0; qq < 4; ++qq) {
            short8 bv;
#pragma unroll
            for (int i = 0; i < 8; ++i)
                bv[i] = ldsh(bW, cb + (size_t)(kg + qq * 8 + i) * H_DIM, isf);
            *(short8*)(&Bs[col][kg + qq * 8]) = bv;
        }
    }
    __syncthreads();

    floatx4 acc[2][4];
#pragma unroll
    for (int i = 0; i < 2; ++i)
#pragma unroll
        for (int jj = 0; jj < 4; ++jj) acc[i][jj] = (floatx4){0.f,0.f,0.f,0.f};
    const int m0 = wv * 32;
#pragma unroll
    for (int kk = 0; kk < 4; ++kk) {
        int k0 = kk * 32;
        short8 a0 = *(const short8*)(&As[m0 + l15][k0 + q * 8]);
        short8 a1 = *(const short8*)(&As[m0 + 16 + l15][k0 + q * 8]);
#pragma unroll
        for (int nt = 0; nt < 4; ++nt) {
            short8 bfr = *(const short8*)(&Bs[nt * 16 + l15][k0 + q * 8]);
            acc[0][nt] = mfma16(a0, bfr, acc[0][nt]);
            acc[1][nt] = mfma16(a1, bfr, acc[1][nt]);
        }
    }
    __syncthreads();
#pragma unroll
    for (int mt = 0; mt < 2; ++mt)
#pragma unroll
        for (int nt = 0; nt < 4; ++nt)
#pragma unroll
            for (int r = 0; r < 4; ++r)
                Cs[m0 + mt * 16 + q * 4 + r][nt * 16 + l15] = acc[mt][nt][r];
    __syncthreads();
    {   // phase A: BN + relu + z[src] gather (f32)
        int j = tid & 63, eg = (tid >> 6) * 32;
        float sc = scale1[nc * 64 + j], sh = shift1[nc * 64 + j];
#pragma unroll 4
        for (int e = eg; e < eg + 32; ++e) {
            float y = Cs[e][j] * sc + sh;
            y = y > 0.f ? y : 0.f;
            y += Z[(size_t)srcl[e] * H_DIM + nc * 64 + j];
            Cs[e][j] = y;
        }
    }
    __syncthreads();   // all reads of Z cells done before in-place writes
    {   // phase B: segment-sum by dst; z += agg (f32, cell-exclusive)
        int j = tid & 63, base = (tid >> 6) * 8;
        float aa[8];
#pragma unroll
        for (int r = 0; r < 8; ++r) aa[r] = 0.f;
        for (int e = 0; e < 128; ++e) {
            float v = Cs[e][j];
            int d = dstl[e] - base;
#pragma unroll
            for (int r = 0; r < 8; ++r) aa[r] += (d == r) ? v : 0.f;
        }
        int nbase = g * NPG + base;
        int cb = nc * 64 + j;
#pragma unroll
        for (int r = 0; r < 8; ++r) {
            size_t idx = (size_t)(nbase + r) * H_DIM + cb;
            X2[idx] = aa[r] + Z[idx];
        }
    }
}

// ---- generic GEMM tile 128x128, bf16 MFMA, flexible A/C dtypes ----
// aMode: 0 = bf16 raw, 1 = f32 (convert), 2 = bf16 + fused BN(scale,shift)+relu
// C dtype: f32 if (outfp? *outfp : cF32) else bf16
__global__ __launch_bounds__(256)
void k_gemm(const void* __restrict__ A, int aMode,
            const float* __restrict__ bnsc, const float* __restrict__ bnsh,
            const void* __restrict__ Bw, size_t boff,
            const void* __restrict__ bias, size_t biasoff,
            void* __restrict__ Cv, int cF32, const int* __restrict__ outfp,
            int K, int lda, int ldb, int ldc,
            const int* __restrict__ flagp)
{
    const int isf = *flagp;
    const int cf  = outfp ? *outfp : cF32;
    const int tid  = threadIdx.x;
    const int lane = tid & 63;
    const int wv   = tid >> 6;
    const int q    = lane >> 4;
    const int l15  = lane & 15;
    const int nb   = blockIdx.x;
    const int mb   = blockIdx.y;

    __shared__ __align__(16) bf16 As[128][40];
    __shared__ __align__(16) bf16 Bs[128][40];

    floatx4 acc[2][8];
#pragma unroll
    for (int i = 0; i < 2; ++i)
#pragma unroll
        for (int j = 0; j < 8; ++j) acc[i][j] = (floatx4){0.f,0.f,0.f,0.f};

    const int arow = tid >> 1;
    const int aoff = (tid & 1) * 16;
    const size_t abase = (size_t)(mb * 128 + arow) * lda + aoff;

    const int bk0 = (tid >> 7) * 16;
    const size_t bbase = boff + (size_t)nb * 128 + (tid & 127);

    for (int k0 = 0; k0 < K; k0 += 32) {
        short av[16];
        if (aMode == 1) {
            const float* Ap = (const float*)A + abase + k0;
#pragma unroll
            for (int i = 0; i < 16; i += 4) {
                float4 f = *(const float4*)(Ap + i);
                bf16 h0 = f2b(f.x), h1 = f2b(f.y), h2 = f2b(f.z), h3 = f2b(f.w);
                av[i+0] = *(short*)&h0; av[i+1] = *(short*)&h1;
                av[i+2] = *(short*)&h2; av[i+3] = *(short*)&h3;
            }
        } else {
            const bf16* Ap = (const bf16*)A + abase + k0;
            *(uint4*)&av[0] = *(const uint4*)Ap;
            *(uint4*)&av[8] = *(const uint4*)(Ap + 8);
            if (aMode == 2) {
#pragma unroll
                for (int i = 0; i < 16; ++i) {
                    bf16 h = *(bf16*)&av[i];
                    float f = b2f(h) * bnsc[k0 + aoff + i] + bnsh[k0 + aoff + i];
                    f = f > 0.f ? f : 0.f;
                    bf16 o = f2b(f);
                    av[i] = *(short*)&o;
                }
            }
        }
        short8 bv0, bv1;
#pragma unroll
        for (int i = 0; i < 8; ++i)
            bv0[i] = ldsh(Bw, bbase + (size_t)(k0 + bk0 + i) * ldb, isf);
#pragma unroll
        for (int i = 0; i < 8; ++i)
            bv1[i] = ldsh(Bw, bbase + (size_t)(k0 + bk0 + 8 + i) * ldb, isf);
        __syncthreads();
        *(uint4*)(&As[arow][aoff])     = *(uint4*)&av[0];
        *(uint4*)(&As[arow][aoff + 8]) = *(uint4*)&av[8];
        *(short8*)(&Bs[tid & 127][bk0])     = bv0;
        *(short8*)(&Bs[tid & 127][bk0 + 8]) = bv1;
        __syncthreads();
        short8 a0 = *(const short8*)(&As[wv * 32 + l15][q * 8]);
        short8 a1 = *(const short8*)(&As[wv * 32 + 16 + l15][q * 8]);
#pragma unroll
        for (int nt = 0; nt < 8; ++nt) {
            short8 bfr = *(const short8*)(&Bs[nt * 16 + l15][q * 8]);
            acc[0][nt] = mfma16(a0, bfr, acc[0][nt]);
            acc[1][nt] = mfma16(a1, bfr, acc[1][nt]);
        }
    }

    float bvv[8];
#pragma unroll
    for (int nt = 0; nt < 8; ++nt)
        bvv[nt] = bias ? ldf(bias, biasoff + nb * 128 + nt * 16 + l15, isf) : 0.f;
#pragma unroll
    for (int mt = 0; mt < 2; ++mt)
#pragma unroll
        for (int r = 0; r < 4; ++r) {
            int row = mb * 128 + wv * 32 + mt * 16 + q * 4 + r;
            size_t cb = (size_t)row * ldc + nb * 128;
            if (cf) {
                float* Crow = (float*)Cv + cb;
#pragma unroll
                for (int nt = 0; nt < 8; ++nt)
                    Crow[nt * 16 + l15] = acc[mt][nt][r] + bvv[nt];
            } else {
                bf16* Crow = (bf16*)Cv + cb;
#pragma unroll
                for (int nt = 0; nt < 8; ++nt)
                    Crow[nt * 16 + l15] = f2b(acc[mt][nt][r] + bvv[nt]);
            }
        }
}

// ---------------- column stats (dtf: 1 = f32 input, 0 = bf16) ----------------
__global__ __launch_bounds__(256)
void k_colstats(const void* __restrict__ X, int dtf, int cols,
                float* __restrict__ cs, float* __restrict__ cq)
{
    const int c0 = blockIdx.x * 64;
    const int rb = blockIdx.y;
    const int c = threadIdx.x & 63, rg = threadIdx.x >> 6;
    const size_t base = (size_t)(rb * 512 + rg) * cols + c0 + c;
    float s = 0.f, sq = 0.f;
    for (int i = 0; i < 128; ++i) {
        size_t idx = base + (size_t)i * 4 * cols;
        float v = dtf ? ((const float*)X)[idx] : b2f(((const bf16*)X)[idx]);
        s += v; sq += v * v;
    }
    __shared__ float red[4][64][2];
    red[rg][c][0] = s; red[rg][c][1] = sq;
    __syncthreads();
    if (threadIdx.x < 64) {
        float ts = red[0][c][0] + red[1][c][0] + red[2][c][0] + red[3][c][0];
        float tq = red[0][c][1] + red[1][c][1] + red[2][c][1] + red[3][c][1];
        atomicAdd(cs + c0 + c, ts);
        atomicAdd(cq + c0 + c, tq);
    }
}

__global__ __launch_bounds__(256)
void k_bn_finalize(const float* __restrict__ cs, const float* __restrict__ cq,
                   const void* __restrict__ g, const void* __restrict__ be, size_t goff,
                   int cols, float invR, float* __restrict__ scale, float* __restrict__ shift,
                   const int* __restrict__ flagp)
{
    const int isf = *flagp;
    int c = blockIdx.x * 256 + threadIdx.x;
    if (c < cols) {
        float mean = cs[c] * invR;
        float var = cq[c] * invR - mean * mean;
        var = var < 0.f ? 0.f : var;
        float rstd = rsqrtf(var + 1e-5f);
        float sc = ldf(g, goff + c, isf) * rstd;
        scale[c] = sc;
        shift[c] = ldf(be, goff + c, isf) - mean * sc;
    }
}

// in-place BN+relu over f32 z
__global__ __launch_bounds__(256)
void k_bn_apply_relu_f32(float* __restrict__ X, const float* __restrict__ scale,
                         const float* __restrict__ shift, int colmask, unsigned int nvec4)
{
    unsigned int i = blockIdx.x * 256 + threadIdx.x;
    if (i >= nvec4) return;
    float4* p = (float4*)X + i;
    int cbase = (int)(((size_t)i * 4) & (size_t)colmask);
    float4 v = *p;
    float f;
    f = v.x * scale[cbase+0] + shift[cbase+0]; v.x = f > 0.f ? f : 0.f;
    f = v.y * scale[cbase+1] + shift[cbase+1]; v.y = f > 0.f ? f : 0.f;
    f = v.z * scale[cbase+2] + shift[cbase+2]; v.z = f > 0.f ? f : 0.f;
    f = v.w * scale[cbase+3] + shift[cbase+3]; v.w = f > 0.f ? f : 0.f;
    *p = v;
}

// ---------------- attention tail ----------------
__global__ __launch_bounds__(256)
void k_att_v(const void* __restrict__ gapW, const void* __restrict__ gapB,
             const void* __restrict__ attW, const void* __restrict__ attB,
             float* __restrict__ v, const int* __restrict__ flagp)
{
    const int isf = *flagp;
    const int lane = threadIdx.x & 63, wv = threadIdx.x >> 6;
    if (blockIdx.x == 256) {
        if (wv == 0) {
            float s = 0.f;
            for (int k = lane; k < 512; k += 64) s += ldf(gapB, k, isf) * ldf(attW, k, isf);
            for (int off = 32; off > 0; off >>= 1) s += __shfl_down(s, off, 64);
            if (lane == 0) v[1024] = s + ldf(attB, 0, isf);
        }
        return;
    }
    const int o = blockIdx.x * 4 + wv;
    float s = 0.f;
    for (int k = lane; k < 512; k += 64) s += ldf(gapW, (size_t)o * 512 + k, isf) * ldf(attW, k, isf);
    for (int off = 32; off > 0; off >>= 1) s += __shfl_down(s, off, 64);
    if (lane == 0) v[o] = s;
}

__global__ __launch_bounds__(256)
void k_qv(const void* __restrict__ outW, const void* __restrict__ outB,
          const float* __restrict__ v, float* __restrict__ qv, const int* __restrict__ flagp)
{
    const int isf = *flagp;
    const int lane = threadIdx.x & 63, wv = threadIdx.x >> 6;
    if (blockIdx.x == 128) {
        if (wv == 0) {
            float s = 0.f;
            for (int o = lane; o < 1024; o += 64) s += ldf(outB, o, isf) * v[o];
            for (int off = 32; off > 0; off >>= 1) s += __shfl_down(s, off, 64);
            if (lane == 0) qv[512] = s + v[1024];
        }
        return;
    }
    const int k = blockIdx.x * 4 + wv;
    float s = 0.f;
    for (int o = lane; o < 1024; o += 64) s += ldf(outW, (size_t)k * 1024 + o, isf) * v[o];
    for (int off = 32; off > 0; off >>= 1) s += __shfl_down(s, off, 64);
    if (lane == 0) qv[k] = s;
}

__global__ __launch_bounds__(256)
void k_att_dot(const float* __restrict__ Z, const float* __restrict__ qv, float* __restrict__ att)
{
    const int lane = threadIdx.x & 63, wv = threadIdx.x >> 6;
    const int row = blockIdx.x * 4 + wv;
    const float* p = Z + (size_t)row * 512 + lane * 8;
    float s = 0.f;
#pragma unroll
    for (int i = 0; i < 8; ++i) s += p[i] * qv[lane * 8 + i];
    for (int off = 32; off > 0; off >>= 1) s += __shfl_down(s, off, 64);
    if (lane == 0) att[row] = s + qv[512];
}

__global__ __launch_bounds__(256)
void k_softmax_pool(const float* __restrict__ Z, const float* __restrict__ att, bf16* __restrict__ ZG)
{
    const int g = blockIdx.x, t = threadIdx.x;
    __shared__ float alpha[32];
    if (t < 32) alpha[t] = att[g * 32 + t];
    __syncthreads();
    if (t == 0) {
        float mx = alpha[0];
        for (int p = 1; p < 32; ++p) mx = fmaxf(mx, alpha[p]);
        float sum = 0.f;
        for (int p = 0; p < 32; ++p) { float e = __expf(alpha[p] - mx); alpha[p] = e; sum += e; }
        float inv = 1.f / sum;
        for (int p = 0; p < 32; ++p) alpha[p] *= inv;
    }
    __syncthreads();
#pragma unroll
    for (int ci = 0; ci < 2; ++ci) {
        int c = t + ci * 256;
        float acc = 0.f;
        for (int p = 0; p < 32; ++p)
            acc += alpha[p] * Z[(size_t)(g * 32 + p) * 512 + c];
        ZG[(size_t)g * 512 + c] = f2b(acc);
    }
}

// ---------------- launcher ----------------
extern "C" void kernel_launch(void* const* d_in, const int* in_sizes, int n_in,
                              void* d_out, int out_size, void* d_ws, size_t ws_size,
                              hipStream_t stream)
{
    (void)in_sizes; (void)n_in; (void)out_size; (void)ws_size;
    const int*  x          = (const int*)d_in[0];
    const int*  edge_attr  = (const int*)d_in[1];
    const int*  edge_index = (const int*)d_in[2];
    const void* node_tab   = d_in[4];
    const void* edge_tab   = d_in[5];
    const void* bondW      = d_in[6];
    const void* bondG      = d_in[8];
    const void* bondBeta   = d_in[9];
    const void* atomW1     = d_in[10];
    const void* atomG      = d_in[12];
    const void* atomBeta   = d_in[13];
    const void* atomW2     = d_in[14];
    const void* normG      = d_in[16];
    const void* normB      = d_in[17];
    const void* outW       = d_in[18];
    const void* outB       = d_in[19];
    const void* gapW       = d_in[20];
    const void* gapB       = d_in[21];
    const void* attW       = d_in[22];
    const void* attB       = d_in[23];
    const void* projW      = d_in[24];
    const void* projB      = d_in[25];

    // workspace: z f32 64MB + Uc bf16 16MB + stats ~220KB = 84.1 MB (proven < ws_size)
    char* ws = (char*)d_ws;
    float* z  = (float*)ws;                       // [0, 64M)
    bf16*  Uc = (bf16*)(ws + 67108864ull);        // [64M, 80M): 8192 x 1024
    char*  st = ws + 83886080ull;
    int*   flag = (int*)(st + 0);
    float* S   = (float*)(st + 256);     // 65536 B
    float* mu  = (float*)(st + 65792);   // 512 B
    float* cs  = (float*)(st + 66304);   // 4096 B
    float* cq  = (float*)(st + 70400);   // 4096 B
    float* sc  = (float*)(st + 74496);   // 4096 B
    float* sh  = (float*)(st + 78592);   // 4096 B
    float* vv  = (float*)(st + 82688);   // 1025 f
    float* qv  = (float*)(st + 87040);   // 513 f
    float* att = (float*)(st + 89344);   // 32768 f
    bf16*  zg  = Uc;                               // 1024x512 bf16 (Uc dead by then)
    bf16*  hg  = (bf16*)((char*)Uc + 1048576);     // 1024x1024 bf16

    k_detect<<<1, 256, 0, stream>>>((const unsigned short*)node_tab, 4096, flag);
    hipMemsetAsync(st + 256, 0, 66048, stream);            // S + mu
    k_bond_stats<<<256, 256, 0, stream>>>(edge_attr, edge_tab, S, mu, flag);
    k_node_embed<<<N_NODES, 512, 0, stream>>>(x, node_tab, z, flag);

    for (int l = 0; l < N_LAYERS; ++l) {
        size_t bWo  = (size_t)l * 128 * 512;
        size_t bGo  = (size_t)l * 512;
        size_t aW1o = (size_t)l * 512 * 1024;
        size_t aGo  = (size_t)l * 1024;
        size_t aW2o = (size_t)l * 1024 * 512;

        k_bond_fold<<<512, 128, 0, stream>>>(S, mu, bondW, bWo, bondG, bondBeta, bGo, sc, sh, flag);
        k_bond_gemm_agg<<<dim3(8, N_GRAPH), 256, 0, stream>>>(edge_attr, edge_tab, bondW, bWo,
                                                              edge_index, z, sc, sh, z, flag);

        // atom MLP pass 1: stats of U (bf16-stored) over all 4 node chunks
        hipMemsetAsync(cs, 0, 8192, stream);
        for (int mc = 0; mc < 4; ++mc) {
            k_gemm<<<dim3(8, 64), 256, 0, stream>>>(z + (size_t)mc * MC_ROWS * 512, 1, nullptr, nullptr,
                                                    atomW1, aW1o, nullptr, 0,
                                                    Uc, 0, nullptr, 512, 512, 1024, 1024, flag);
            k_colstats<<<dim3(16, 16), 256, 0, stream>>>(Uc, 0, 1024, cs, cq);
        }
        k_bn_finalize<<<4, 256, 0, stream>>>(cs, cq, atomG, atomBeta, aGo, 1024, 1.f / 32768.f, sc, sh, flag);

        // pass 2: recompute U chunk (chunk 3 still resident), fused-BN GEMM2 -> z f32 in place
        for (int mi = 0; mi < 4; ++mi) {
            int mc = (mi + 3) & 3;   // order: 3,0,1,2 — skip recompute for 3
            if (mc != 3)
                k_gemm<<<dim3(8, 64), 256, 0, stream>>>(z + (size_t)mc * MC_ROWS * 512, 1, nullptr, nullptr,
                                                        atomW1, aW1o, nullptr, 0,
                                                        Uc, 0, nullptr, 512, 512, 1024, 1024, flag);
            k_gemm<<<dim3(4, 64), 256, 0, stream>>>(Uc, 2, sc, sh,
                                                    atomW2, aW2o, nullptr, 0,
                                                    z + (size_t)mc * MC_ROWS * 512, 1, nullptr,
                                                    1024, 1024, 512, 512, flag);
        }

        // outer BN + relu on f32 z
        hipMemsetAsync(cs, 0, 8192, stream);
        k_colstats<<<dim3(8, 64), 256, 0, stream>>>(z, 1, 512, cs, cq);
        k_bn_finalize<<<2, 256, 0, stream>>>(cs, cq, normG, normB, bGo, 512, 1.f / 32768.f, sc, sh, flag);
        k_bn_apply_relu_f32<<<16384, 256, 0, stream>>>(z, sc, sh, 511, 4194304u);
    }

    k_att_v<<<257, 256, 0, stream>>>(gapW, gapB, attW, attB, vv, flag);
    k_qv<<<129, 256, 0, stream>>>(outW, outB, vv, qv, flag);
    k_att_dot<<<8192, 256, 0, stream>>>(z, qv, att);
    k_softmax_pool<<<N_GRAPH, 256, 0, stream>>>(z, att, zg);
    // hg = zg @ outW + outB
    k_gemm<<<dim3(8, 8), 256, 0, stream>>>(zg, 0, nullptr, nullptr, outW, 0, outB, 0,
                                           hg, 0, nullptr, 512, 512, 1024, 1024, flag);
    // out = hg @ projW + projB (dtype follows detected input dtype)
    k_gemm<<<dim3(8, 8), 256, 0, stream>>>(hg, 0, nullptr, nullptr, projW, 0, projB, 0,
                                           d_out, 0, flag, 1024, 1024, 1024, 1024, flag);
}

// Round 5
// 5450.125 us; speedup vs baseline: 2.3171x; 2.3171x over previous
//
#include <hip/hip_runtime.h>
#include <hip/hip_bf16.h>
#include <stdint.h>

using bf16 = __hip_bfloat16;
typedef __attribute__((ext_vector_type(8))) short short8;
typedef __attribute__((ext_vector_type(4))) float floatx4;

#define N_NODES  32768
#define N_EDGES  131072
#define N_GRAPH  1024
#define NPG      32
#define EPG      128
#define H_DIM    512
#define HE_DIM   128
#define OUT_DIM  1024
#define N_LAYERS 6
#define MC_ROWS  8192

__device__ __forceinline__ float b2f(bf16 v) { return __bfloat162float(v); }
__device__ __forceinline__ bf16  f2b(float f) { return __float2bfloat16(f); }
__device__ __forceinline__ floatx4 mfma16(short8 a, short8 b, floatx4 c) {
    return __builtin_amdgcn_mfma_f32_16x16x32_bf16(a, b, c, 0, 0, 0);
}
// dual-dtype load for external tensors (runtime-detected flag; proven bf16)
__device__ __forceinline__ float ldf(const void* p, size_t i, int isf) {
    return isf ? ((const float*)p)[i] : b2f(((const bf16*)p)[i]);
}
// async global->LDS 16B DMA: LDS dest is wave-uniform base + lane*16
__device__ __forceinline__ void gload_lds16(const void* g, void* l) {
    __builtin_amdgcn_global_load_lds(
        (const __attribute__((address_space(1))) unsigned int*)g,
        (__attribute__((address_space(3))) unsigned int*)l, 16, 0, 0);
}

__device__ const int NODE_OFFS[9] = {0,119,128,139,151,160,165,173,175};

// ---------- dtype detection ----------
__global__ __launch_bounds__(256)
void k_detect(const unsigned short* __restrict__ tab, int n, int* __restrict__ flag)
{
    int big = 0;
    for (int i = threadIdx.x; i < n; i += 256) {
        unsigned short u = tab[i];
        int e = (u >> 7) & 0xFF;
        if (e >= 0x88) big++;
    }
    __shared__ int r[256];
    r[threadIdx.x] = big;
    __syncthreads();
    for (int s = 128; s > 0; s >>= 1) {
        if (threadIdx.x < s) r[threadIdx.x] += r[threadIdx.x + s];
        __syncthreads();
    }
    if (threadIdx.x == 0) *flag = (r[0] > 64) ? 1 : 0;
}

// ---------- transpose W[K][N] (external dtype) -> Wt[N][K] bf16 ----------
__global__ __launch_bounds__(256)
void k_transpose(const void* __restrict__ W, size_t woff, bf16* __restrict__ Wt,
                 int K, int N, const int* __restrict__ flagp)
{
    const int isf = *flagp;
    __shared__ bf16 tile[64][72];   // 72: 16B-aligned rows + conflict-spread columns
    const int nb = blockIdx.x * 64, kb = blockIdx.y * 64;
    const int t = threadIdx.x;
    const int r = t >> 2, c0 = (t & 3) * 16;
    if (isf) {
        const float* src = (const float*)W + woff + (size_t)(kb + r) * N + nb + c0;
#pragma unroll
        for (int i = 0; i < 16; ++i) tile[r][c0 + i] = f2b(src[i]);
    } else {
        const bf16* src = (const bf16*)W + woff + (size_t)(kb + r) * N + nb + c0;
        *(uint4*)&tile[r][c0]     = ((const uint4*)src)[0];
        *(uint4*)&tile[r][c0 + 8] = ((const uint4*)src)[1];
    }
    __syncthreads();
    __align__(16) bf16 vals[16];
#pragma unroll
    for (int i = 0; i < 16; ++i) vals[i] = tile[c0 + i][r];
    bf16* dst = Wt + (size_t)(nb + r) * K + kb + c0;
    *(uint4*)dst       = *(uint4*)&vals[0];
    *(uint4*)(dst + 8) = *(uint4*)&vals[8];
}

// ---------------- node embedding -> f32 z ----------------
__global__ __launch_bounds__(512)
void k_node_embed(const int* __restrict__ x, const void* __restrict__ tab,
                  float* __restrict__ Z, const int* __restrict__ flagp)
{
    const int isf = *flagp;
    const int n = blockIdx.x, t = threadIdx.x;
    __shared__ int xi[9];
    if (t < 9) xi[t] = NODE_OFFS[t] + x[(size_t)n * 9 + t];
    __syncthreads();
    float s = 0.f;
#pragma unroll
    for (int f = 0; f < 9; ++f) s += ldf(tab, (size_t)xi[f] * H_DIM + t, isf);
    Z[(size_t)n * H_DIM + t] = s;
}

// ------- bond BN stats from tables: mu = sum_e e, S = e^T e (bf16-rounded e) -------
__global__ __launch_bounds__(256)
void k_bond_stats(const int* __restrict__ ea, const void* __restrict__ etab,
                  float* __restrict__ S, float* __restrict__ mu, const int* __restrict__ flagp)
{
    const int isf = *flagp;
    __shared__ float ebuf[8][128];
    const int tid = threadIdx.x;
    const int i  = tid >> 1;
    const int j0 = (tid & 1) * 64;
    float sacc[64];
#pragma unroll
    for (int t = 0; t < 64; ++t) sacc[t] = 0.f;
    float muacc = 0.f;
    const int e0 = blockIdx.x * 512;
    for (int c = 0; c < 64; ++c) {
        __syncthreads();
        {
            int el = tid >> 5, cc = (tid & 31) * 4;
            int e = e0 + c * 8 + el;
            int i0 = ea[(size_t)e * 3 + 0];
            int i1 = 119 + ea[(size_t)e * 3 + 1];
            int i2 = 128 + ea[(size_t)e * 3 + 2];
#pragma unroll
            for (int j = 0; j < 4; ++j) {
                float s = ldf(etab, (size_t)i0 * HE_DIM + cc + j, isf)
                        + ldf(etab, (size_t)i1 * HE_DIM + cc + j, isf)
                        + ldf(etab, (size_t)i2 * HE_DIM + cc + j, isf);
                ebuf[el][cc + j] = b2f(f2b(s));
            }
        }
        __syncthreads();
#pragma unroll
        for (int e = 0; e < 8; ++e) {
            float ei = ebuf[e][i];
            if (tid < 128) muacc += ebuf[e][tid];
            const float4* row = (const float4*)(&ebuf[e][j0]);
#pragma unroll
            for (int jj = 0; jj < 16; ++jj) {
                float4 vv = row[jj];
                sacc[jj*4+0] += ei * vv.x;
                sacc[jj*4+1] += ei * vv.y;
                sacc[jj*4+2] += ei * vv.z;
                sacc[jj*4+3] += ei * vv.w;
            }
        }
    }
    float* Sp = S + (size_t)i * 128 + j0;
#pragma unroll
    for (int t = 0; t < 64; ++t) atomicAdd(Sp + t, sacc[t]);
    if (tid < 128) atomicAdd(mu + tid, muacc);
}

// ------- per-layer fold: bond BN scale/shift (bias cancels in BN) -------
__global__ __launch_bounds__(128)
void k_bond_fold(const float* __restrict__ S, const float* __restrict__ mu,
                 const bf16* __restrict__ bWt,
                 const void* __restrict__ bG, const void* __restrict__ bBe, size_t go,
                 float* __restrict__ scale1, float* __restrict__ shift1,
                 const int* __restrict__ flagp)
{
    const int isf = *flagp;
    const int j = blockIdx.x;   // 0..511
    const int k = threadIdx.x;  // 0..127
    __shared__ float wbuf[128];
    __shared__ float rp[2][2];
    wbuf[k] = b2f(bWt[(size_t)j * 128 + k]);
    __syncthreads();
    float wk = wbuf[k];
    float dot = 0.f;
    for (int m = 0; m < 128; ++m) dot += S[(size_t)m * 128 + k] * wbuf[m];
    float p1 = wk * dot;
    float p2 = mu[k] * wk;
    for (int off = 32; off > 0; off >>= 1) {
        p1 += __shfl_down(p1, off, 64);
        p2 += __shfl_down(p2, off, 64);
    }
    if ((k & 63) == 0) { rp[k >> 6][0] = p1; rp[k >> 6][1] = p2; }
    __syncthreads();
    if (k == 0) {
        const float invE = 1.f / (float)N_EDGES;
        float mean = (rp[0][1] + rp[1][1]) * invE;
        float var  = (rp[0][0] + rp[1][0]) * invE - mean * mean;
        var = var < 0.f ? 0.f : var;
        float rstd = rsqrtf(var + 1e-5f);
        float sc = ldf(bG, go + j, isf) * rstd;
        scale1[j] = sc;
        shift1[j] = ldf(bBe, go + j, isf) - mean * sc;
    }
}

// --- fused: e recompute; ee=relu(BN(e@bW)); msg=z[src]+ee; agg by dst; z+=agg (f32) ---
__global__ __launch_bounds__(256)
void k_bond_gemm_agg(const int* __restrict__ ea, const void* __restrict__ etab,
                     const bf16* __restrict__ bWt,
                     const int* __restrict__ edge_index, const float* __restrict__ Z,
                     const float* __restrict__ scale1, const float* __restrict__ shift1,
                     float* __restrict__ X2, const int* __restrict__ flagp)
{
    const int isf = *flagp;
    const int tid = threadIdx.x;
    const int lane = tid & 63, wv = tid >> 6, q = lane >> 4, l15 = lane & 15;
    const int nc = blockIdx.x;   // col chunk (64 of 512)
    const int g  = blockIdx.y;   // graph

    __shared__ __align__(16) char smem[54784];
    bf16 (*As)[136] = (bf16(*)[136])smem;               // 128 edges x 128 K
    bf16 (*Bs)[136] = (bf16(*)[136])(smem + 34816);     // 64 cols x 128 K
    float (*Cs)[68] = (float(*)[68])smem;               // aliases As after MFMA
    int* srcl = (int*)(smem + 52224);
    int* dstl = srcl + 128;
    int (*eix)[3] = (int(*)[3])(smem + 53248);

    if (tid < 128) {
        int e = g * EPG + tid;
        srcl[tid] = edge_index[e];
        dstl[tid] = edge_index[N_EDGES + e] - g * NPG;
        eix[tid][0] = ea[(size_t)e * 3 + 0];
        eix[tid][1] = 119 + ea[(size_t)e * 3 + 1];
        eix[tid][2] = 128 + ea[(size_t)e * 3 + 2];
    }
    __syncthreads();
    {   // stage A: recompute edge embedding, 2 threads per row
        int row = tid >> 1, half = (tid & 1) * 64;
        int eb[3] = {eix[row][0], eix[row][1], eix[row][2]};
#pragma unroll
        for (int seg = 0; seg < 4; ++seg) {
            float a16[16];
#pragma unroll
            for (int j = 0; j < 16; ++j) a16[j] = 0.f;
#pragma unroll
            for (int f = 0; f < 3; ++f) {
                size_t base = (size_t)eb[f] * HE_DIM + half + seg * 16;
                if (isf) {
                    const float4* s = (const float4*)((const float*)etab + base);
#pragma unroll
                    for (int v = 0; v < 4; ++v) {
                        float4 t = s[v];
                        a16[v*4+0] += t.x; a16[v*4+1] += t.y;
                        a16[v*4+2] += t.z; a16[v*4+3] += t.w;
                    }
                } else {
                    const bf16* s = (const bf16*)etab + base;
#pragma unroll
                    for (int j = 0; j < 16; ++j) a16[j] += b2f(s[j]);
                }
            }
#pragma unroll
            for (int j = 0; j < 16; ++j) As[row][half + seg * 16 + j] = f2b(a16[j]);
        }
    }
    {   // stage B^T from pre-transposed bWt [512][128]: coalesced vector loads
        int row = tid >> 2, seg = (tid & 3) * 32;
        const bf16* src = bWt + (size_t)(nc * 64 + row) * 128 + seg;
        uint4 v0 = ((const uint4*)src)[0];
        uint4 v1 = ((const uint4*)src)[1];
        uint4 v2 = ((const uint4*)src)[2];
        uint4 v3 = ((const uint4*)src)[3];
        *(uint4*)(&Bs[row][seg +  0]) = v0;
        *(uint4*)(&Bs[row][seg +  8]) = v1;
        *(uint4*)(&Bs[row][seg + 16]) = v2;
        *(uint4*)(&Bs[row][seg + 24]) = v3;
    }
    __syncthreads();

    floatx4 acc[2][4];
#pragma unroll
    for (int i = 0; i < 2; ++i)
#pragma unroll
        for (int jj = 0; jj < 4; ++jj) acc[i][jj] = (floatx4){0.f,0.f,0.f,0.f};
    const int m0 = wv * 32;
#pragma unroll
    for (int kk = 0; kk < 4; ++kk) {
        int k0 = kk * 32;
        short8 a0 = *(const short8*)(&As[m0 + l15][k0 + q * 8]);
        short8 a1 = *(const short8*)(&As[m0 + 16 + l15][k0 + q * 8]);
#pragma unroll
        for (int nt = 0; nt < 4; ++nt) {
            short8 bfr = *(const short8*)(&Bs[nt * 16 + l15][k0 + q * 8]);
            acc[0][nt] = mfma16(a0, bfr, acc[0][nt]);
            acc[1][nt] = mfma16(a1, bfr, acc[1][nt]);
        }
    }
    __syncthreads();
#pragma unroll
    for (int mt = 0; mt < 2; ++mt)
#pragma unroll
        for (int nt = 0; nt < 4; ++nt)
#pragma unroll
            for (int r = 0; r < 4; ++r)
                Cs[m0 + mt * 16 + q * 4 + r][nt * 16 + l15] = acc[mt][nt][r];
    __syncthreads();
    {   // phase A: BN + relu + z[src] gather (f32)
        int j = tid & 63, eg = (tid >> 6) * 32;
        float sc = scale1[nc * 64 + j], sh = shift1[nc * 64 + j];
#pragma unroll 4
        for (int e = eg; e < eg + 32; ++e) {
            float y = Cs[e][j] * sc + sh;
            y = y > 0.f ? y : 0.f;
            y += Z[(size_t)srcl[e] * H_DIM + nc * 64 + j];
            Cs[e][j] = y;
        }
    }
    __syncthreads();
    {   // phase B: segment-sum by dst; z += agg (cell-exclusive, in-place safe)
        int j = tid & 63, base = (tid >> 6) * 8;
        float aa[8];
#pragma unroll
        for (int r = 0; r < 8; ++r) aa[r] = 0.f;
        for (int e = 0; e < 128; ++e) {
            float v = Cs[e][j];
            int d = dstl[e] - base;
#pragma unroll
            for (int r = 0; r < 8; ++r) aa[r] += (d == r) ? v : 0.f;
        }
        int nbase = g * NPG + base;
        int cb = nc * 64 + j;
#pragma unroll
        for (int r = 0; r < 8; ++r) {
            size_t idx = (size_t)(nbase + r) * H_DIM + cb;
            X2[idx] = aa[r] + Z[idx];
        }
    }
}

// ---- fast GEMM: C[128x128 tiles] = A[M,K] @ Bt^T, Bt pre-transposed [N][K] bf16 ----
// aMode: 0 = bf16 raw, 1 = f32 (convert), 2 = bf16 + fused BN(scale,shift)+relu
// cMode: 0 = no store, 1 = bf16, 2 = f32, 3 = flag-dependent (f32 if *flagp)
// statsMode: 0 none, 1 = column stats of bf16-rounded values, 2 = of f32 values
__global__ __launch_bounds__(256, 2)
void k_gemm(const void* __restrict__ Av, int aMode,
            const float* __restrict__ bnsc, const float* __restrict__ bnsh,
            const bf16* __restrict__ Bt,
            void* __restrict__ Cv, int cMode,
            const void* __restrict__ bias, const int* __restrict__ flagp,
            int statsMode, float* __restrict__ cs, float* __restrict__ cq,
            int K, int lda, int ldc)
{
    const int tid  = threadIdx.x;
    const int lane = tid & 63;
    const int wv   = tid >> 6;
    const int q    = lane >> 4;
    const int l15  = lane & 15;
    const int wm   = wv & 1;
    const int wn   = wv >> 1;
    const int m0   = blockIdx.y * 128;
    const int n0   = blockIdx.x * 128;

    __shared__ __align__(16) bf16 As[128][40];   // padded (VGPR-staged)
    __shared__ __align__(16) bf16 Bs[128][32];   // unpadded (DMA: base + lane*16)

    floatx4 acc[4][4];
#pragma unroll
    for (int mt = 0; mt < 4; ++mt)
#pragma unroll
        for (int nt = 0; nt < 4; ++nt) acc[mt][nt] = (floatx4){0.f,0.f,0.f,0.f};

    const int ar = tid >> 1;
    const int ak = (tid & 1) * 16;
    const bf16* BtBase = Bt + (size_t)n0 * K;
    const int cb0 = wv * 64;         // B chunk bases (chunk = 16B unit of Bs)
    const int cb1 = (4 + wv) * 64;

    for (int k0 = 0; k0 < K; k0 += 32) {
        // A: global -> VGPR (issued before barrier for latency overlap)
        short av[16];
        if (aMode == 1) {
            const float* Ap = (const float*)Av + (size_t)(m0 + ar) * lda + k0 + ak;
#pragma unroll
            for (int i = 0; i < 16; i += 4) {
                float4 f = *(const float4*)(Ap + i);
                bf16 h0 = f2b(f.x), h1 = f2b(f.y), h2 = f2b(f.z), h3 = f2b(f.w);
                av[i] = *(short*)&h0; av[i+1] = *(short*)&h1;
                av[i+2] = *(short*)&h2; av[i+3] = *(short*)&h3;
            }
        } else {
            const bf16* Ap = (const bf16*)Av + (size_t)(m0 + ar) * lda + k0 + ak;
            *(uint4*)&av[0] = *(const uint4*)Ap;
            *(uint4*)&av[8] = *(const uint4*)(Ap + 8);
            if (aMode == 2) {
#pragma unroll
                for (int i = 0; i < 16; ++i) {
                    bf16 h = *(bf16*)&av[i];
                    float f = b2f(h) * bnsc[k0 + ak + i] + bnsh[k0 + ak + i];
                    f = f > 0.f ? f : 0.f;
                    bf16 o = f2b(f);
                    av[i] = *(short*)&o;
                }
            }
        }
        __syncthreads();   // prior iteration's LDS reads complete
        {   // B: async DMA into Bs (2 x 1KB per wave)
            int c0i = cb0 + lane;
            gload_lds16(BtBase + (size_t)(c0i >> 2) * K + k0 + (c0i & 3) * 8,
                        &Bs[0][0] + (size_t)cb0 * 8);
            int c1i = cb1 + lane;
            gload_lds16(BtBase + (size_t)(c1i >> 2) * K + k0 + (c1i & 3) * 8,
                        &Bs[0][0] + (size_t)cb1 * 8);
        }
        *(uint4*)(&As[ar][ak])     = *(uint4*)&av[0];
        *(uint4*)(&As[ar][ak + 8]) = *(uint4*)&av[8];
        __syncthreads();   // drains DMA (vmcnt) + LDS writes
        short8 af[4], bfr[4];
#pragma unroll
        for (int mt = 0; mt < 4; ++mt)
            af[mt] = *(const short8*)(&As[wm * 64 + mt * 16 + l15][q * 8]);
#pragma unroll
        for (int nt = 0; nt < 4; ++nt)
            bfr[nt] = *(const short8*)(&Bs[wn * 64 + nt * 16 + l15][q * 8]);
#pragma unroll
        for (int mt = 0; mt < 4; ++mt)
#pragma unroll
            for (int nt = 0; nt < 4; ++nt)
                acc[mt][nt] = mfma16(af[mt], bfr[nt], acc[mt][nt]);
    }

    const int isf = flagp ? *flagp : 0;
    int cm = cMode;
    if (cMode == 3) cm = isf ? 2 : 1;
    float bvv[4] = {0.f, 0.f, 0.f, 0.f};
    if (bias) {
#pragma unroll
        for (int nt = 0; nt < 4; ++nt)
            bvv[nt] = ldf(bias, (size_t)n0 + wn * 64 + nt * 16 + l15, isf);
    }
    if (cm) {
#pragma unroll
        for (int mt = 0; mt < 4; ++mt)
#pragma unroll
            for (int r = 0; r < 4; ++r) {
                int row = m0 + wm * 64 + mt * 16 + q * 4 + r;
                if (cm == 2) {
                    float* Crow = (float*)Cv + (size_t)row * ldc + n0;
#pragma unroll
                    for (int nt = 0; nt < 4; ++nt)
                        Crow[wn * 64 + nt * 16 + l15] = acc[mt][nt][r] + bvv[nt];
                } else {
                    bf16* Crow = (bf16*)Cv + (size_t)row * ldc + n0;
#pragma unroll
                    for (int nt = 0; nt < 4; ++nt)
                        Crow[wn * 64 + nt * 16 + l15] = f2b(acc[mt][nt][r] + bvv[nt]);
                }
            }
    }
    if (statsMode) {
        float ls[4], lq[4];
#pragma unroll
        for (int nt = 0; nt < 4; ++nt) { ls[nt] = 0.f; lq[nt] = 0.f; }
#pragma unroll
        for (int nt = 0; nt < 4; ++nt)
#pragma unroll
            for (int mt = 0; mt < 4; ++mt)
#pragma unroll
                for (int r = 0; r < 4; ++r) {
                    float v = acc[mt][nt][r];
                    if (statsMode == 1) v = b2f(f2b(v));   // stats of rounded store
                    ls[nt] += v; lq[nt] += v * v;
                }
        float* red = (float*)&As[0][0];
        __syncthreads();
        red[tid] = 0.f;   // 128 cols x {sum, sumsq}
        __syncthreads();
#pragma unroll
        for (int nt = 0; nt < 4; ++nt) {
            int col = wn * 64 + nt * 16 + l15;
            atomicAdd(&red[col * 2],     ls[nt]);
            atomicAdd(&red[col * 2 + 1], lq[nt]);
        }
        __syncthreads();
        if (tid < 128) {
            atomicAdd(&cs[n0 + tid], red[tid * 2]);
            atomicAdd(&cq[n0 + tid], red[tid * 2 + 1]);
        }
    }
}

__global__ __launch_bounds__(256)
void k_bn_finalize(const float* __restrict__ cs, const float* __restrict__ cq,
                   const void* __restrict__ g, const void* __restrict__ be, size_t goff,
                   int cols, float invR, float* __restrict__ scale, float* __restrict__ shift,
                   const int* __restrict__ flagp)
{
    const int isf = *flagp;
    int c = blockIdx.x * 256 + threadIdx.x;
    if (c < cols) {
        float mean = cs[c] * invR;
        float var = cq[c] * invR - mean * mean;
        var = var < 0.f ? 0.f : var;
        float rstd = rsqrtf(var + 1e-5f);
        float sc = ldf(g, goff + c, isf) * rstd;
        scale[c] = sc;
        shift[c] = ldf(be, goff + c, isf) - mean * sc;
    }
}

__global__ __launch_bounds__(256)
void k_bn_apply_relu_f32(float* __restrict__ X, const float* __restrict__ scale,
                         const float* __restrict__ shift, int colmask, unsigned int nvec4)
{
    unsigned int i = blockIdx.x * 256 + threadIdx.x;
    if (i >= nvec4) return;
    float4* p = (float4*)X + i;
    int cbase = (int)(((size_t)i * 4) & (size_t)colmask);
    float4 v = *p;
    float f;
    f = v.x * scale[cbase+0] + shift[cbase+0]; v.x = f > 0.f ? f : 0.f;
    f = v.y * scale[cbase+1] + shift[cbase+1]; v.y = f > 0.f ? f : 0.f;
    f = v.z * scale[cbase+2] + shift[cbase+2]; v.z = f > 0.f ? f : 0.f;
    f = v.w * scale[cbase+3] + shift[cbase+3]; v.w = f > 0.f ? f : 0.f;
    *p = v;
}

// ---------------- attention tail ----------------
__global__ __launch_bounds__(256)
void k_att_v(const void* __restrict__ gapW, const void* __restrict__ gapB,
             const void* __restrict__ attW, const void* __restrict__ attB,
             float* __restrict__ v, const int* __restrict__ flagp)
{
    const int isf = *flagp;
    const int lane = threadIdx.x & 63, wv = threadIdx.x >> 6;
    if (blockIdx.x == 256) {
        if (wv == 0) {
            float s = 0.f;
            for (int k = lane; k < 512; k += 64) s += ldf(gapB, k, isf) * ldf(attW, k, isf);
            for (int off = 32; off > 0; off >>= 1) s += __shfl_down(s, off, 64);
            if (lane == 0) v[1024] = s + ldf(attB, 0, isf);
        }
        return;
    }
    const int o = blockIdx.x * 4 + wv;
    float s = 0.f;
    for (int k = lane; k < 512; k += 64) s += ldf(gapW, (size_t)o * 512 + k, isf) * ldf(attW, k, isf);
    for (int off = 32; off > 0; off >>= 1) s += __shfl_down(s, off, 64);
    if (lane == 0) v[o] = s;
}

__global__ __launch_bounds__(256)
void k_qv(const void* __restrict__ outW, const void* __restrict__ outB,
          const float* __restrict__ v, float* __restrict__ qv, const int* __restrict__ flagp)
{
    const int isf = *flagp;
    const int lane = threadIdx.x & 63, wv = threadIdx.x >> 6;
    if (blockIdx.x == 128) {
        if (wv == 0) {
            float s = 0.f;
            for (int o = lane; o < 1024; o += 64) s += ldf(outB, o, isf) * v[o];
            for (int off = 32; off > 0; off >>= 1) s += __shfl_down(s, off, 64);
            if (lane == 0) qv[512] = s + v[1024];
        }
        return;
    }
    const int k = blockIdx.x * 4 + wv;
    float s = 0.f;
    for (int o = lane; o < 1024; o += 64) s += ldf(outW, (size_t)k * 1024 + o, isf) * v[o];
    for (int off = 32; off > 0; off >>= 1) s += __shfl_down(s, off, 64);
    if (lane == 0) qv[k] = s;
}

__global__ __launch_bounds__(256)
void k_att_dot(const float* __restrict__ Z, const float* __restrict__ qv, float* __restrict__ att)
{
    const int lane = threadIdx.x & 63, wv = threadIdx.x >> 6;
    const int row = blockIdx.x * 4 + wv;
    const float* p = Z + (size_t)row * 512 + lane * 8;
    float s = 0.f;
#pragma unroll
    for (int i = 0; i < 8; ++i) s += p[i] * qv[lane * 8 + i];
    for (int off = 32; off > 0; off >>= 1) s += __shfl_down(s, off, 64);
    if (lane == 0) att[row] = s + qv[512];
}

__global__ __launch_bounds__(256)
void k_softmax_pool(const float* __restrict__ Z, const float* __restrict__ att, bf16* __restrict__ ZG)
{
    const int g = blockIdx.x, t = threadIdx.x;
    __shared__ float alpha[32];
    if (t < 32) alpha[t] = att[g * 32 + t];
    __syncthreads();
    if (t == 0) {
        float mx = alpha[0];
        for (int p = 1; p < 32; ++p) mx = fmaxf(mx, alpha[p]);
        float sum = 0.f;
        for (int p = 0; p < 32; ++p) { float e = __expf(alpha[p] - mx); alpha[p] = e; sum += e; }
        float inv = 1.f / sum;
        for (int p = 0; p < 32; ++p) alpha[p] *= inv;
    }
    __syncthreads();
#pragma unroll
    for (int ci = 0; ci < 2; ++ci) {
        int c = t + ci * 256;
        float acc = 0.f;
        for (int p = 0; p < 32; ++p)
            acc += alpha[p] * Z[(size_t)(g * 32 + p) * 512 + c];
        ZG[(size_t)g * 512 + c] = f2b(acc);
    }
}

// ---------------- launcher ----------------
extern "C" void kernel_launch(void* const* d_in, const int* in_sizes, int n_in,
                              void* d_out, int out_size, void* d_ws, size_t ws_size,
                              hipStream_t stream)
{
    (void)in_sizes; (void)n_in; (void)out_size; (void)ws_size;
    const int*  x          = (const int*)d_in[0];
    const int*  edge_attr  = (const int*)d_in[1];
    const int*  edge_index = (const int*)d_in[2];
    const void* node_tab   = d_in[4];
    const void* edge_tab   = d_in[5];
    const void* bondW      = d_in[6];
    const void* bondG      = d_in[8];
    const void* bondBeta   = d_in[9];
    const void* atomW1     = d_in[10];
    const void* atomG      = d_in[12];
    const void* atomBeta   = d_in[13];
    const void* atomW2     = d_in[14];
    const void* normG      = d_in[16];
    const void* normB      = d_in[17];
    const void* outW       = d_in[18];
    const void* outB       = d_in[19];
    const void* gapW       = d_in[20];
    const void* gapB       = d_in[21];
    const void* attW       = d_in[22];
    const void* attB       = d_in[23];
    const void* projW      = d_in[24];
    const void* projB      = d_in[25];

    // workspace layout (max used = 86,342,912 B < 87,253,504 proven-safe)
    char* ws = (char*)d_ws;
    float* z      = (float*)ws;                              // 64 MB
    bf16*  Uc     = (bf16*)(ws + 67108864ull);               // 16 MB (8192x1024)
    bf16*  zg     = Uc;                                      // tail overlay (1 MB)
    bf16*  hg     = (bf16*)(ws + 67108864ull + 1048576ull);  // tail overlay (2 MB)
    bf16*  projWt = (bf16*)(ws + 67108864ull + 4194304ull);  // tail overlay (2 MB)
    bf16*  W1t    = (bf16*)(ws + 83886080ull);               // 1 MB
    bf16*  W2t    = (bf16*)(ws + 84934656ull);               // 1 MB
    bf16*  bWt    = (bf16*)(ws + 85983232ull);               // 128 KB
    bf16*  outWt  = W1t;                                     // tail overlay
    char*  st  = ws + 86114304ull;
    int*   flag = (int*)(st);
    float* S    = (float*)(st + 256);
    float* mu   = (float*)(st + 65792);
    float* cs   = (float*)(st + 66304);
    float* cq   = (float*)(st + 70400);
    float* sc1  = (float*)(st + 74496);
    float* sh1  = (float*)(st + 78592);
    float* cs2  = (float*)(st + 82688);
    float* cq2  = (float*)(st + 84736);
    float* sc2  = (float*)(st + 86784);
    float* sh2  = (float*)(st + 88832);
    float* vv   = (float*)(st + 90880);
    float* qv   = (float*)(st + 95232);
    float* att  = (float*)(st + 97536);

    k_detect<<<1, 256, 0, stream>>>((const unsigned short*)node_tab, 4096, flag);
    hipMemsetAsync(st + 256, 0, 66048, stream);   // S + mu
    k_bond_stats<<<256, 256, 0, stream>>>(edge_attr, edge_tab, S, mu, flag);
    k_node_embed<<<N_NODES, 512, 0, stream>>>(x, node_tab, z, flag);

    for (int l = 0; l < N_LAYERS; ++l) {
        k_transpose<<<dim3(16, 8), 256, 0, stream>>>(atomW1, (size_t)l * 512 * 1024, W1t, 512, 1024, flag);
        k_transpose<<<dim3(8, 16), 256, 0, stream>>>(atomW2, (size_t)l * 1024 * 512, W2t, 1024, 512, flag);
        k_transpose<<<dim3(8, 2), 256, 0, stream>>>(bondW, (size_t)l * 128 * 512, bWt, 128, 512, flag);

        k_bond_fold<<<512, 128, 0, stream>>>(S, mu, bWt, bondG, bondBeta, (size_t)l * 512, sc1, sh1, flag);
        k_bond_gemm_agg<<<dim3(8, N_GRAPH), 256, 0, stream>>>(edge_attr, edge_tab, bWt,
                                                              edge_index, z, sc1, sh1, z, flag);

        // atom MLP pass 1: BN1 stats over full M (no C store; stats of rounded values)
        hipMemsetAsync(cs, 0, 8192, stream);
        k_gemm<<<dim3(8, 256), 256, 0, stream>>>(z, 1, nullptr, nullptr, W1t,
                                                 nullptr, 0, nullptr, nullptr,
                                                 1, cs, cq, 512, 512, 0);
        k_bn_finalize<<<4, 256, 0, stream>>>(cs, cq, atomG, atomBeta, (size_t)l * 1024,
                                             1024, 1.f / 32768.f, sc1, sh1, flag);
        // pass 2 per node chunk: recompute U -> Uc; GEMM2 (fused BN1 on A) -> z f32 (+BN2 stats)
        hipMemsetAsync(cs2, 0, 4096, stream);
        for (int mc = 0; mc < 4; ++mc) {
            float* zc = z + (size_t)mc * MC_ROWS * 512;
            k_gemm<<<dim3(8, 64), 256, 0, stream>>>(zc, 1, nullptr, nullptr, W1t,
                                                    Uc, 1, nullptr, nullptr,
                                                    0, nullptr, nullptr, 512, 512, 1024);
            k_gemm<<<dim3(4, 64), 256, 0, stream>>>(Uc, 2, sc1, sh1, W2t,
                                                    zc, 2, nullptr, nullptr,
                                                    2, cs2, cq2, 1024, 1024, 512);
        }
        k_bn_finalize<<<2, 256, 0, stream>>>(cs2, cq2, normG, normB, (size_t)l * 512,
                                             512, 1.f / 32768.f, sc2, sh2, flag);
        k_bn_apply_relu_f32<<<16384, 256, 0, stream>>>(z, sc2, sh2, 511, 4194304u);
    }

    k_att_v<<<257, 256, 0, stream>>>(gapW, gapB, attW, attB, vv, flag);
    k_qv<<<129, 256, 0, stream>>>(outW, outB, vv, qv, flag);
    k_att_dot<<<8192, 256, 0, stream>>>(z, qv, att);
    k_softmax_pool<<<N_GRAPH, 256, 0, stream>>>(z, att, zg);
    k_transpose<<<dim3(16, 8), 256, 0, stream>>>(outW, 0, outWt, 512, 1024, flag);
    k_gemm<<<dim3(8, 8), 256, 0, stream>>>(zg, 0, nullptr, nullptr, outWt,
                                           hg, 1, outB, flag,
                                           0, nullptr, nullptr, 512, 512, 1024);
    k_transpose<<<dim3(16, 16), 256, 0, stream>>>(projW, 0, projWt, 1024, 1024, flag);
    k_gemm<<<dim3(8, 8), 256, 0, stream>>>(hg, 0, nullptr, nullptr, projWt,
                                           d_out, 3, projB, flag,
                                           0, nullptr, nullptr, 1024, 1024, 1024);
}

// Round 6
// 4740.424 us; speedup vs baseline: 2.6640x; 1.1497x over previous
//
#include <hip/hip_runtime.h>
#include <hip/hip_bf16.h>
#include <stdint.h>

using bf16 = __hip_bfloat16;
typedef __attribute__((ext_vector_type(8))) short short8;
typedef __attribute__((ext_vector_type(4))) float floatx4;

#define N_NODES  32768
#define N_EDGES  131072
#define N_GRAPH  1024
#define NPG      32
#define EPG      128
#define H_DIM    512
#define HE_DIM   128
#define OUT_DIM  1024
#define N_LAYERS 6
#define MC_ROWS  8192

__device__ __forceinline__ float b2f(bf16 v) { return __bfloat162float(v); }
__device__ __forceinline__ bf16  f2b(float f) { return __float2bfloat16(f); }
__device__ __forceinline__ floatx4 mfma16(short8 a, short8 b, floatx4 c) {
    return __builtin_amdgcn_mfma_f32_16x16x32_bf16(a, b, c, 0, 0, 0);
}
__device__ __forceinline__ float ldf(const void* p, size_t i, int isf) {
    return isf ? ((const float*)p)[i] : b2f(((const bf16*)p)[i]);
}
__device__ __forceinline__ void gload_lds16(const void* g, void* l) {
    __builtin_amdgcn_global_load_lds(
        (const __attribute__((address_space(1))) unsigned int*)g,
        (__attribute__((address_space(3))) unsigned int*)l, 16, 0, 0);
}

__device__ const int NODE_OFFS[9] = {0,119,128,139,151,160,165,173,175};

// ---------- dtype detection ----------
__global__ __launch_bounds__(256)
void k_detect(const unsigned short* __restrict__ tab, int n, int* __restrict__ flag)
{
    int big = 0;
    for (int i = threadIdx.x; i < n; i += 256) {
        unsigned short u = tab[i];
        int e = (u >> 7) & 0xFF;
        if (e >= 0x88) big++;
    }
    __shared__ int r[256];
    r[threadIdx.x] = big;
    __syncthreads();
    for (int s = 128; s > 0; s >>= 1) {
        if (threadIdx.x < s) r[threadIdx.x] += r[threadIdx.x + s];
        __syncthreads();
    }
    if (threadIdx.x == 0) *flag = (r[0] > 64) ? 1 : 0;
}

// ---------- transpose W[K][N] (external dtype) -> Wt[N][K] bf16 ----------
__global__ __launch_bounds__(256)
void k_transpose(const void* __restrict__ W, size_t woff, bf16* __restrict__ Wt,
                 int K, int N, const int* __restrict__ flagp)
{
    const int isf = *flagp;
    __shared__ bf16 tile[64][72];
    const int nb = blockIdx.x * 64, kb = blockIdx.y * 64;
    const int t = threadIdx.x;
    const int r = t >> 2, c0 = (t & 3) * 16;
    if (isf) {
        const float* src = (const float*)W + woff + (size_t)(kb + r) * N + nb + c0;
#pragma unroll
        for (int i = 0; i < 16; ++i) tile[r][c0 + i] = f2b(src[i]);
    } else {
        const bf16* src = (const bf16*)W + woff + (size_t)(kb + r) * N + nb + c0;
        *(uint4*)&tile[r][c0]     = ((const uint4*)src)[0];
        *(uint4*)&tile[r][c0 + 8] = ((const uint4*)src)[1];
    }
    __syncthreads();
    __align__(16) bf16 vals[16];
#pragma unroll
    for (int i = 0; i < 16; ++i) vals[i] = tile[c0 + i][r];
    bf16* dst = Wt + (size_t)(nb + r) * K + kb + c0;
    *(uint4*)dst       = *(uint4*)&vals[0];
    *(uint4*)(dst + 8) = *(uint4*)&vals[8];
}

// ---------------- node embedding -> f32 z ----------------
__global__ __launch_bounds__(512)
void k_node_embed(const int* __restrict__ x, const void* __restrict__ tab,
                  float* __restrict__ Z, const int* __restrict__ flagp)
{
    const int isf = *flagp;
    const int n = blockIdx.x, t = threadIdx.x;
    __shared__ int xi[9];
    if (t < 9) xi[t] = NODE_OFFS[t] + x[(size_t)n * 9 + t];
    __syncthreads();
    float s = 0.f;
#pragma unroll
    for (int f = 0; f < 9; ++f) s += ldf(tab, (size_t)xi[f] * H_DIM + t, isf);
    Z[(size_t)n * H_DIM + t] = s;
}

// ------- bond Gram via MFMA: S += E^T E, mu += colsum(E); E recomputed from tables -------
// 256 blocks x 512 edges; E staged transposed (Et[col][edge]) so A/B frags are contiguous.
__global__ __launch_bounds__(256)
void k_bond_gram(const int* __restrict__ ea, const void* __restrict__ etab,
                 float* __restrict__ S, float* __restrict__ mu, const int* __restrict__ flagp)
{
    const int isf = *flagp;
    const int tid = threadIdx.x;
    const int lane = tid & 63, wv = tid >> 6, q = lane >> 4, l15 = lane & 15;
    __shared__ __align__(16) bf16 Et[128][136];   // [col][edge-slice], 16B-aligned rows
    __shared__ int eix[128][3];

    floatx4 acc[2][8];
#pragma unroll
    for (int i = 0; i < 2; ++i)
#pragma unroll
        for (int j = 0; j < 8; ++j) acc[i][j] = (floatx4){0.f,0.f,0.f,0.f};
    float muacc = 0.f;
    const int e0 = blockIdx.x * 512;

    for (int r = 0; r < 4; ++r) {       // 4 slices of 128 edges
        __syncthreads();                // prior slice's MFMA reads complete
        if (tid < 128) {
            int e = e0 + r * 128 + tid;
            eix[tid][0] = ea[(size_t)e * 3 + 0];
            eix[tid][1] = 119 + ea[(size_t)e * 3 + 1];
            eix[tid][2] = 128 + ea[(size_t)e * 3 + 2];
        }
        __syncthreads();
        {   // stage transposed: thread (c, eh) covers 64 edges of column c
            int c = tid & 127, eh = (tid >> 7) * 64;
            for (int e = eh; e < eh + 64; e += 2) {
                float s0 = ldf(etab, (size_t)eix[e][0] * HE_DIM + c, isf)
                         + ldf(etab, (size_t)eix[e][1] * HE_DIM + c, isf)
                         + ldf(etab, (size_t)eix[e][2] * HE_DIM + c, isf);
                float s1 = ldf(etab, (size_t)eix[e+1][0] * HE_DIM + c, isf)
                         + ldf(etab, (size_t)eix[e+1][1] * HE_DIM + c, isf)
                         + ldf(etab, (size_t)eix[e+1][2] * HE_DIM + c, isf);
                bf16 h0 = f2b(s0), h1 = f2b(s1);
                unsigned int pk = (unsigned int)*(unsigned short*)&h0
                                | ((unsigned int)*(unsigned short*)&h1 << 16);
                *(unsigned int*)&Et[c][e] = pk;
                muacc += b2f(h0) + b2f(h1);
            }
        }
        __syncthreads();
        // Gram MFMA: wave wv handles i-tiles {2wv, 2wv+1} x j-tiles 0..7
#pragma unroll
        for (int kc = 0; kc < 4; ++kc) {
            short8 a0 = *(const short8*)&Et[wv * 32 + l15][kc * 32 + q * 8];
            short8 a1 = *(const short8*)&Et[wv * 32 + 16 + l15][kc * 32 + q * 8];
#pragma unroll
            for (int nt = 0; nt < 8; ++nt) {
                short8 b = *(const short8*)&Et[nt * 16 + l15][kc * 32 + q * 8];
                acc[0][nt] = mfma16(a0, b, acc[0][nt]);
                acc[1][nt] = mfma16(a1, b, acc[1][nt]);
            }
        }
    }
#pragma unroll
    for (int mt = 0; mt < 2; ++mt)
#pragma unroll
        for (int nt = 0; nt < 8; ++nt)
#pragma unroll
            for (int rr = 0; rr < 4; ++rr) {
                int row = wv * 32 + mt * 16 + q * 4 + rr;
                atomicAdd(&S[(size_t)row * 128 + nt * 16 + l15], acc[mt][nt][rr]);
            }
    atomicAdd(&mu[tid & 127], muacc);
}

// ------- per-layer fold: bond BN scale/shift (bias cancels in BN) -------
__global__ __launch_bounds__(128)
void k_bond_fold(const float* __restrict__ S, const float* __restrict__ mu,
                 const bf16* __restrict__ bWt,
                 const void* __restrict__ bG, const void* __restrict__ bBe, size_t go,
                 float* __restrict__ scale1, float* __restrict__ shift1,
                 const int* __restrict__ flagp)
{
    const int isf = *flagp;
    const int j = blockIdx.x;
    const int k = threadIdx.x;
    __shared__ float wbuf[128];
    __shared__ float rp[2][2];
    wbuf[k] = b2f(bWt[(size_t)j * 128 + k]);
    __syncthreads();
    float wk = wbuf[k];
    float dot = 0.f;
    for (int m = 0; m < 128; ++m) dot += S[(size_t)m * 128 + k] * wbuf[m];
    float p1 = wk * dot;
    float p2 = mu[k] * wk;
    for (int off = 32; off > 0; off >>= 1) {
        p1 += __shfl_down(p1, off, 64);
        p2 += __shfl_down(p2, off, 64);
    }
    if ((k & 63) == 0) { rp[k >> 6][0] = p1; rp[k >> 6][1] = p2; }
    __syncthreads();
    if (k == 0) {
        const float invE = 1.f / (float)N_EDGES;
        float mean = (rp[0][1] + rp[1][1]) * invE;
        float var  = (rp[0][0] + rp[1][0]) * invE - mean * mean;
        var = var < 0.f ? 0.f : var;
        float rstd = rsqrtf(var + 1e-5f);
        float sc = ldf(bG, go + j, isf) * rstd;
        scale1[j] = sc;
        shift1[j] = ldf(bBe, go + j, isf) - mean * sc;
    }
}

// --- fused: e recompute; ee=relu(BN(e@bW)); msg=bn2(z)[src]+ee; agg; z=bn2(z)+agg ---
// zsc/zsh: previous layer's outer-BN scale/shift applied to all z reads (nullptr = raw z)
__global__ __launch_bounds__(256)
void k_bond_gemm_agg(const int* __restrict__ ea, const void* __restrict__ etab,
                     const bf16* __restrict__ bWt,
                     const int* __restrict__ edge_index, const float* __restrict__ Z,
                     const float* __restrict__ scale1, const float* __restrict__ shift1,
                     const float* __restrict__ zsc, const float* __restrict__ zsh,
                     float* __restrict__ X2, const int* __restrict__ flagp)
{
    const int isf = *flagp;
    const int tid = threadIdx.x;
    const int lane = tid & 63, wv = tid >> 6, q = lane >> 4, l15 = lane & 15;
    const int nc = blockIdx.x;
    const int g  = blockIdx.y;

    __shared__ __align__(16) char smem[54784];
    bf16 (*As)[136] = (bf16(*)[136])smem;
    bf16 (*Bs)[136] = (bf16(*)[136])(smem + 34816);
    float (*Cs)[68] = (float(*)[68])smem;
    int* srcl = (int*)(smem + 52224);
    int* dstl = srcl + 128;
    int (*eix)[3] = (int(*)[3])(smem + 53248);

    if (tid < 128) {
        int e = g * EPG + tid;
        srcl[tid] = edge_index[e];
        dstl[tid] = edge_index[N_EDGES + e] - g * NPG;
        eix[tid][0] = ea[(size_t)e * 3 + 0];
        eix[tid][1] = 119 + ea[(size_t)e * 3 + 1];
        eix[tid][2] = 128 + ea[(size_t)e * 3 + 2];
    }
    __syncthreads();
    {   // stage A: recompute edge embedding, 2 threads per row
        int row = tid >> 1, half = (tid & 1) * 64;
        int eb[3] = {eix[row][0], eix[row][1], eix[row][2]};
#pragma unroll
        for (int seg = 0; seg < 4; ++seg) {
            float a16[16];
#pragma unroll
            for (int j = 0; j < 16; ++j) a16[j] = 0.f;
#pragma unroll
            for (int f = 0; f < 3; ++f) {
                size_t base = (size_t)eb[f] * HE_DIM + half + seg * 16;
                if (isf) {
                    const float4* s = (const float4*)((const float*)etab + base);
#pragma unroll
                    for (int v = 0; v < 4; ++v) {
                        float4 t = s[v];
                        a16[v*4+0] += t.x; a16[v*4+1] += t.y;
                        a16[v*4+2] += t.z; a16[v*4+3] += t.w;
                    }
                } else {
                    const bf16* s = (const bf16*)etab + base;
#pragma unroll
                    for (int j = 0; j < 16; ++j) a16[j] += b2f(s[j]);
                }
            }
#pragma unroll
            for (int j = 0; j < 16; ++j) As[row][half + seg * 16 + j] = f2b(a16[j]);
        }
    }
    {   // stage B^T from bWt [512][128]
        int row = tid >> 2, seg = (tid & 3) * 32;
        const bf16* src = bWt + (size_t)(nc * 64 + row) * 128 + seg;
        uint4 v0 = ((const uint4*)src)[0];
        uint4 v1 = ((const uint4*)src)[1];
        uint4 v2 = ((const uint4*)src)[2];
        uint4 v3 = ((const uint4*)src)[3];
        *(uint4*)(&Bs[row][seg +  0]) = v0;
        *(uint4*)(&Bs[row][seg +  8]) = v1;
        *(uint4*)(&Bs[row][seg + 16]) = v2;
        *(uint4*)(&Bs[row][seg + 24]) = v3;
    }
    __syncthreads();

    floatx4 acc[2][4];
#pragma unroll
    for (int i = 0; i < 2; ++i)
#pragma unroll
        for (int jj = 0; jj < 4; ++jj) acc[i][jj] = (floatx4){0.f,0.f,0.f,0.f};
    const int m0 = wv * 32;
#pragma unroll
    for (int kk = 0; kk < 4; ++kk) {
        int k0 = kk * 32;
        short8 a0 = *(const short8*)(&As[m0 + l15][k0 + q * 8]);
        short8 a1 = *(const short8*)(&As[m0 + 16 + l15][k0 + q * 8]);
#pragma unroll
        for (int nt = 0; nt < 4; ++nt) {
            short8 bfr = *(const short8*)(&Bs[nt * 16 + l15][k0 + q * 8]);
            acc[0][nt] = mfma16(a0, bfr, acc[0][nt]);
            acc[1][nt] = mfma16(a1, bfr, acc[1][nt]);
        }
    }
    __syncthreads();
#pragma unroll
    for (int mt = 0; mt < 2; ++mt)
#pragma unroll
        for (int nt = 0; nt < 4; ++nt)
#pragma unroll
            for (int r = 0; r < 4; ++r)
                Cs[m0 + mt * 16 + q * 4 + r][nt * 16 + l15] = acc[mt][nt][r];
    __syncthreads();
    {   // phase A: bond-BN + relu + bn2(z)[src] gather
        int j = tid & 63, eg = (tid >> 6) * 32;
        int col = nc * 64 + j;
        float sc = scale1[col], sh = shift1[col];
        float zs = zsc ? zsc[col] : 1.f, zh = zsc ? zsh[col] : 0.f;
#pragma unroll 4
        for (int e = eg; e < eg + 32; ++e) {
            float y = Cs[e][j] * sc + sh;
            y = y > 0.f ? y : 0.f;
            float zv = Z[(size_t)srcl[e] * H_DIM + col];
            if (zsc) { zv = zv * zs + zh; zv = zv > 0.f ? zv : 0.f; }
            Cs[e][j] = y + zv;
        }
    }
    __syncthreads();
    {   // phase B: segment-sum by dst; z = bn2(z) + agg (cell-exclusive, in-place safe)
        int j = tid & 63, base = (tid >> 6) * 8;
        int col = nc * 64 + j;
        float zs = zsc ? zsc[col] : 1.f, zh = zsc ? zsh[col] : 0.f;
        float aa[8];
#pragma unroll
        for (int r = 0; r < 8; ++r) aa[r] = 0.f;
        for (int e = 0; e < 128; ++e) {
            float v = Cs[e][j];
            int d = dstl[e] - base;
#pragma unroll
            for (int r = 0; r < 8; ++r) aa[r] += (d == r) ? v : 0.f;
        }
        int nbase = g * NPG + base;
#pragma unroll
        for (int r = 0; r < 8; ++r) {
            size_t idx = (size_t)(nbase + r) * H_DIM + col;
            float zv = Z[idx];
            if (zsc) { zv = zv * zs + zh; zv = zv > 0.f ? zv : 0.f; }
            X2[idx] = aa[r] + zv;
        }
    }
}

// ---- fast GEMM: C[128x128 tiles] = A[M,K] @ Bt^T, Bt pre-transposed [N][K] bf16 ----
// aMode: 0 bf16 raw, 1 f32 (convert), 2 bf16 + fused BN+relu
// cMode: 0 no store, 1 bf16, 2 f32, 3 flag-dependent
// statsMode: 0 none, 1 stats of bf16-rounded, 2 stats of f32
// mStoreMin: store only rows >= mStoreMin, at C row (row - mStoreMin)
__global__ __launch_bounds__(256, 2)
void k_gemm(const void* __restrict__ Av, int aMode,
            const float* __restrict__ bnsc, const float* __restrict__ bnsh,
            const bf16* __restrict__ Bt,
            void* __restrict__ Cv, int cMode,
            const void* __restrict__ bias, const int* __restrict__ flagp,
            int statsMode, float* __restrict__ cs, float* __restrict__ cq,
            int K, int lda, int ldc, int mStoreMin)
{
    const int tid  = threadIdx.x;
    const int lane = tid & 63;
    const int wv   = tid >> 6;
    const int q    = lane >> 4;
    const int l15  = lane & 15;
    const int wm   = wv & 1;
    const int wn   = wv >> 1;
    const int m0   = blockIdx.y * 128;
    const int n0   = blockIdx.x * 128;

    __shared__ __align__(16) bf16 As[128][40];
    __shared__ __align__(16) bf16 Bs[128][32];

    floatx4 acc[4][4];
#pragma unroll
    for (int mt = 0; mt < 4; ++mt)
#pragma unroll
        for (int nt = 0; nt < 4; ++nt) acc[mt][nt] = (floatx4){0.f,0.f,0.f,0.f};

    const int ar = tid >> 1;
    const int ak = (tid & 1) * 16;
    const bf16* BtBase = Bt + (size_t)n0 * K;
    const int cb0 = wv * 64;
    const int cb1 = (4 + wv) * 64;

    for (int k0 = 0; k0 < K; k0 += 32) {
        short av[16];
        if (aMode == 1) {
            const float* Ap = (const float*)Av + (size_t)(m0 + ar) * lda + k0 + ak;
#pragma unroll
            for (int i = 0; i < 16; i += 4) {
                float4 f = *(const float4*)(Ap + i);
                bf16 h0 = f2b(f.x), h1 = f2b(f.y), h2 = f2b(f.z), h3 = f2b(f.w);
                av[i] = *(short*)&h0; av[i+1] = *(short*)&h1;
                av[i+2] = *(short*)&h2; av[i+3] = *(short*)&h3;
            }
        } else {
            const bf16* Ap = (const bf16*)Av + (size_t)(m0 + ar) * lda + k0 + ak;
            *(uint4*)&av[0] = *(const uint4*)Ap;
            *(uint4*)&av[8] = *(const uint4*)(Ap + 8);
            if (aMode == 2) {
#pragma unroll
                for (int i = 0; i < 16; ++i) {
                    bf16 h = *(bf16*)&av[i];
                    float f = b2f(h) * bnsc[k0 + ak + i] + bnsh[k0 + ak + i];
                    f = f > 0.f ? f : 0.f;
                    bf16 o = f2b(f);
                    av[i] = *(short*)&o;
                }
            }
        }
        __syncthreads();
        {
            int c0i = cb0 + lane;
            gload_lds16(BtBase + (size_t)(c0i >> 2) * K + k0 + (c0i & 3) * 8,
                        &Bs[0][0] + (size_t)cb0 * 8);
            int c1i = cb1 + lane;
            gload_lds16(BtBase + (size_t)(c1i >> 2) * K + k0 + (c1i & 3) * 8,
                        &Bs[0][0] + (size_t)cb1 * 8);
        }
        *(uint4*)(&As[ar][ak])     = *(uint4*)&av[0];
        *(uint4*)(&As[ar][ak + 8]) = *(uint4*)&av[8];
        __syncthreads();
        short8 af[4], bfr[4];
#pragma unroll
        for (int mt = 0; mt < 4; ++mt)
            af[mt] = *(const short8*)(&As[wm * 64 + mt * 16 + l15][q * 8]);
#pragma unroll
        for (int nt = 0; nt < 4; ++nt)
            bfr[nt] = *(const short8*)(&Bs[wn * 64 + nt * 16 + l15][q * 8]);
#pragma unroll
        for (int mt = 0; mt < 4; ++mt)
#pragma unroll
            for (int nt = 0; nt < 4; ++nt)
                acc[mt][nt] = mfma16(af[mt], bfr[nt], acc[mt][nt]);
    }

    const int isf = flagp ? *flagp : 0;
    int cm = cMode;
    if (cMode == 3) cm = isf ? 2 : 1;
    float bvv[4] = {0.f, 0.f, 0.f, 0.f};
    if (bias) {
#pragma unroll
        for (int nt = 0; nt < 4; ++nt)
            bvv[nt] = ldf(bias, (size_t)n0 + wn * 64 + nt * 16 + l15, isf);
    }
    if (cm) {
#pragma unroll
        for (int mt = 0; mt < 4; ++mt)
#pragma unroll
            for (int r = 0; r < 4; ++r) {
                int row = m0 + wm * 64 + mt * 16 + q * 4 + r;
                if (row < mStoreMin) continue;
                size_t crow = (size_t)(row - mStoreMin) * ldc + n0;
                if (cm == 2) {
                    float* Crow = (float*)Cv + crow;
#pragma unroll
                    for (int nt = 0; nt < 4; ++nt)
                        Crow[wn * 64 + nt * 16 + l15] = acc[mt][nt][r] + bvv[nt];
                } else {
                    bf16* Crow = (bf16*)Cv + crow;
#pragma unroll
                    for (int nt = 0; nt < 4; ++nt)
                        Crow[wn * 64 + nt * 16 + l15] = f2b(acc[mt][nt][r] + bvv[nt]);
                }
            }
    }
    if (statsMode) {
        float ls[4], lq[4];
#pragma unroll
        for (int nt = 0; nt < 4; ++nt) { ls[nt] = 0.f; lq[nt] = 0.f; }
#pragma unroll
        for (int nt = 0; nt < 4; ++nt)
#pragma unroll
            for (int mt = 0; mt < 4; ++mt)
#pragma unroll
                for (int r = 0; r < 4; ++r) {
                    float v = acc[mt][nt][r];
                    if (statsMode == 1) v = b2f(f2b(v));
                    ls[nt] += v; lq[nt] += v * v;
                }
        float* red = (float*)&As[0][0];
        __syncthreads();
        red[tid] = 0.f;
        __syncthreads();
#pragma unroll
        for (int nt = 0; nt < 4; ++nt) {
            int col = wn * 64 + nt * 16 + l15;
            atomicAdd(&red[col * 2],     ls[nt]);
            atomicAdd(&red[col * 2 + 1], lq[nt]);
        }
        __syncthreads();
        if (tid < 128) {
            atomicAdd(&cs[n0 + tid], red[tid * 2]);
            atomicAdd(&cq[n0 + tid], red[tid * 2 + 1]);
        }
    }
}

__global__ __launch_bounds__(256)
void k_bn_finalize(const float* __restrict__ cs, const float* __restrict__ cq,
                   const void* __restrict__ g, const void* __restrict__ be, size_t goff,
                   int cols, float invR, float* __restrict__ scale, float* __restrict__ shift,
                   const int* __restrict__ flagp)
{
    const int isf = *flagp;
    int c = blockIdx.x * 256 + threadIdx.x;
    if (c < cols) {
        float mean = cs[c] * invR;
        float var = cq[c] * invR - mean * mean;
        var = var < 0.f ? 0.f : var;
        float rstd = rsqrtf(var + 1e-5f);
        float sc = ldf(g, goff + c, isf) * rstd;
        scale[c] = sc;
        shift[c] = ldf(be, goff + c, isf) - mean * sc;
    }
}

__global__ __launch_bounds__(256)
void k_bn_apply_relu_f32(float* __restrict__ X, const float* __restrict__ scale,
                         const float* __restrict__ shift, int colmask, unsigned int nvec4)
{
    unsigned int i = blockIdx.x * 256 + threadIdx.x;
    if (i >= nvec4) return;
    float4* p = (float4*)X + i;
    int cbase = (int)(((size_t)i * 4) & (size_t)colmask);
    float4 v = *p;
    float f;
    f = v.x * scale[cbase+0] + shift[cbase+0]; v.x = f > 0.f ? f : 0.f;
    f = v.y * scale[cbase+1] + shift[cbase+1]; v.y = f > 0.f ? f : 0.f;
    f = v.z * scale[cbase+2] + shift[cbase+2]; v.z = f > 0.f ? f : 0.f;
    f = v.w * scale[cbase+3] + shift[cbase+3]; v.w = f > 0.f ? f : 0.f;
    *p = v;
}

// ---------------- attention tail ----------------
__global__ __launch_bounds__(256)
void k_att_v(const void* __restrict__ gapW, const void* __restrict__ gapB,
             const void* __restrict__ attW, const void* __restrict__ attB,
             float* __restrict__ v, const int* __restrict__ flagp)
{
    const int isf = *flagp;
    const int lane = threadIdx.x & 63, wv = threadIdx.x >> 6;
    if (blockIdx.x == 256) {
        if (wv == 0) {
            float s = 0.f;
            for (int k = lane; k < 512; k += 64) s += ldf(gapB, k, isf) * ldf(attW, k, isf);
            for (int off = 32; off > 0; off >>= 1) s += __shfl_down(s, off, 64);
            if (lane == 0) v[1024] = s + ldf(attB, 0, isf);
        }
        return;
    }
    const int o = blockIdx.x * 4 + wv;
    float s = 0.f;
    for (int k = lane; k < 512; k += 64) s += ldf(gapW, (size_t)o * 512 + k, isf) * ldf(attW, k, isf);
    for (int off = 32; off > 0; off >>= 1) s += __shfl_down(s, off, 64);
    if (lane == 0) v[o] = s;
}

__global__ __launch_bounds__(256)
void k_qv(const void* __restrict__ outW, const void* __restrict__ outB,
          const float* __restrict__ v, float* __restrict__ qv, const int* __restrict__ flagp)
{
    const int isf = *flagp;
    const int lane = threadIdx.x & 63, wv = threadIdx.x >> 6;
    if (blockIdx.x == 128) {
        if (wv == 0) {
            float s = 0.f;
            for (int o = lane; o < 1024; o += 64) s += ldf(outB, o, isf) * v[o];
            for (int off = 32; off > 0; off >>= 1) s += __shfl_down(s, off, 64);
            if (lane == 0) qv[512] = s + v[1024];
        }
        return;
    }
    const int k = blockIdx.x * 4 + wv;
    float s = 0.f;
    for (int o = lane; o < 1024; o += 64) s += ldf(outW, (size_t)k * 1024 + o, isf) * v[o];
    for (int off = 32; off > 0; off >>= 1) s += __shfl_down(s, off, 64);
    if (lane == 0) qv[k] = s;
}

__global__ __launch_bounds__(256)
void k_att_dot(const float* __restrict__ Z, const float* __restrict__ qv, float* __restrict__ att)
{
    const int lane = threadIdx.x & 63, wv = threadIdx.x >> 6;
    const int row = blockIdx.x * 4 + wv;
    const float* p = Z + (size_t)row * 512 + lane * 8;
    float s = 0.f;
#pragma unroll
    for (int i = 0; i < 8; ++i) s += p[i] * qv[lane * 8 + i];
    for (int off = 32; off > 0; off >>= 1) s += __shfl_down(s, off, 64);
    if (lane == 0) att[row] = s + qv[512];
}

__global__ __launch_bounds__(256)
void k_softmax_pool(const float* __restrict__ Z, const float* __restrict__ att, bf16* __restrict__ ZG)
{
    const int g = blockIdx.x, t = threadIdx.x;
    __shared__ float alpha[32];
    if (t < 32) alpha[t] = att[g * 32 + t];
    __syncthreads();
    if (t == 0) {
        float mx = alpha[0];
        for (int p = 1; p < 32; ++p) mx = fmaxf(mx, alpha[p]);
        float sum = 0.f;
        for (int p = 0; p < 32; ++p) { float e = __expf(alpha[p] - mx); alpha[p] = e; sum += e; }
        float inv = 1.f / sum;
        for (int p = 0; p < 32; ++p) alpha[p] *= inv;
    }
    __syncthreads();
#pragma unroll
    for (int ci = 0; ci < 2; ++ci) {
        int c = t + ci * 256;
        float acc = 0.f;
        for (int p = 0; p < 32; ++p)
            acc += alpha[p] * Z[(size_t)(g * 32 + p) * 512 + c];
        ZG[(size_t)g * 512 + c] = f2b(acc);
    }
}

// ---------------- launcher ----------------
extern "C" void kernel_launch(void* const* d_in, const int* in_sizes, int n_in,
                              void* d_out, int out_size, void* d_ws, size_t ws_size,
                              hipStream_t stream)
{
    (void)in_sizes; (void)n_in; (void)out_size; (void)ws_size;
    const int*  x          = (const int*)d_in[0];
    const int*  edge_attr  = (const int*)d_in[1];
    const int*  edge_index = (const int*)d_in[2];
    const void* node_tab   = d_in[4];
    const void* edge_tab   = d_in[5];
    const void* bondW      = d_in[6];
    const void* bondG      = d_in[8];
    const void* bondBeta   = d_in[9];
    const void* atomW1     = d_in[10];
    const void* atomG      = d_in[12];
    const void* atomBeta   = d_in[13];
    const void* atomW2     = d_in[14];
    const void* normG      = d_in[16];
    const void* normB      = d_in[17];
    const void* outW       = d_in[18];
    const void* outB       = d_in[19];
    const void* gapW       = d_in[20];
    const void* gapB       = d_in[21];
    const void* attW       = d_in[22];
    const void* attB       = d_in[23];
    const void* projW      = d_in[24];
    const void* projB      = d_in[25];

    char* ws = (char*)d_ws;
    float* z      = (float*)ws;                              // 64 MB
    bf16*  Uc     = (bf16*)(ws + 67108864ull);               // 16 MB
    bf16*  zg     = Uc;
    bf16*  hg     = (bf16*)(ws + 67108864ull + 1048576ull);
    bf16*  projWt = (bf16*)(ws + 67108864ull + 4194304ull);
    bf16*  W1t    = (bf16*)(ws + 83886080ull);               // 1 MB
    bf16*  W2t    = (bf16*)(ws + 84934656ull);               // 1 MB
    bf16*  bWt    = (bf16*)(ws + 85983232ull);               // 128 KB
    bf16*  outWt  = W1t;
    char*  st  = ws + 86114304ull;
    int*   flag = (int*)(st);
    float* S    = (float*)(st + 256);       // 64 KB
    float* mu   = (float*)(st + 65792);     // 512 B
    float* cs   = (float*)(st + 66304);     // 4 KB
    float* cq   = (float*)(st + 70400);     // 4 KB
    float* cs2  = (float*)(st + 74496);     // 2 KB
    float* cq2  = (float*)(st + 76544);     // 2 KB
    float* sc1  = (float*)(st + 78592);     // 4 KB
    float* sh1  = (float*)(st + 82688);     // 4 KB
    float* sc2  = (float*)(st + 86784);     // 2 KB
    float* sh2  = (float*)(st + 88832);     // 2 KB
    float* vv   = (float*)(st + 90880);
    float* qv   = (float*)(st + 95232);
    float* att  = (float*)(st + 97536);     // 128 KB

    k_detect<<<1, 256, 0, stream>>>((const unsigned short*)node_tab, 4096, flag);
    hipMemsetAsync(st + 256, 0, 66048, stream);   // S + mu
    k_bond_gram<<<256, 256, 0, stream>>>(edge_attr, edge_tab, S, mu, flag);
    k_node_embed<<<N_NODES, 512, 0, stream>>>(x, node_tab, z, flag);

    for (int l = 0; l < N_LAYERS; ++l) {
        const float* zscp = (l == 0) ? nullptr : sc2;
        const float* zshp = (l == 0) ? nullptr : sh2;

        k_transpose<<<dim3(16, 8), 256, 0, stream>>>(atomW1, (size_t)l * 512 * 1024, W1t, 512, 1024, flag);
        k_transpose<<<dim3(8, 16), 256, 0, stream>>>(atomW2, (size_t)l * 1024 * 512, W2t, 1024, 512, flag);
        k_transpose<<<dim3(8, 2), 256, 0, stream>>>(bondW, (size_t)l * 128 * 512, bWt, 128, 512, flag);

        k_bond_fold<<<512, 128, 0, stream>>>(S, mu, bWt, bondG, bondBeta, (size_t)l * 512, sc1, sh1, flag);
        // bond: applies previous layer's outer BN to z reads; writes raw x2 into z
        k_bond_gemm_agg<<<dim3(8, N_GRAPH), 256, 0, stream>>>(edge_attr, edge_tab, bWt,
                                                              edge_index, z, sc1, sh1,
                                                              zscp, zshp, z, flag);

        hipMemsetAsync(cs, 0, 12288, stream);  // cs, cq, cs2, cq2
        // pass 1: full-M BN1 stats; stores rows 24576.. into Uc (last chunk pre-computed)
        k_gemm<<<dim3(8, 256), 256, 0, stream>>>(z, 1, nullptr, nullptr, W1t,
                                                 Uc, 1, nullptr, nullptr,
                                                 1, cs, cq, 512, 512, 1024, 24576);
        k_bn_finalize<<<4, 256, 0, stream>>>(cs, cq, atomG, atomBeta, (size_t)l * 1024,
                                             1024, 1.f / 32768.f, sc1, sh1, flag);
        // pass 2: chunk 3 first (Uc already holds it), then recompute 0,1,2
        for (int mi = 0; mi < 4; ++mi) {
            int mc = (mi + 3) & 3;
            float* zc = z + (size_t)mc * MC_ROWS * 512;
            if (mc != 3)
                k_gemm<<<dim3(8, 64), 256, 0, stream>>>(zc, 1, nullptr, nullptr, W1t,
                                                        Uc, 1, nullptr, nullptr,
                                                        0, nullptr, nullptr, 512, 512, 1024, 0);
            k_gemm<<<dim3(4, 64), 256, 0, stream>>>(Uc, 2, sc1, sh1, W2t,
                                                    zc, 2, nullptr, nullptr,
                                                    2, cs2, cq2, 1024, 1024, 512, 0);
        }
        k_bn_finalize<<<2, 256, 0, stream>>>(cs2, cq2, normG, normB, (size_t)l * 512,
                                             512, 1.f / 32768.f, sc2, sh2, flag);
    }
    // final outer BN applied explicitly for the tail
    k_bn_apply_relu_f32<<<16384, 256, 0, stream>>>(z, sc2, sh2, 511, 4194304u);

    k_att_v<<<257, 256, 0, stream>>>(gapW, gapB, attW, attB, vv, flag);
    k_qv<<<129, 256, 0, stream>>>(outW, outB, vv, qv, flag);
    k_att_dot<<<8192, 256, 0, stream>>>(z, qv, att);
    k_softmax_pool<<<N_GRAPH, 256, 0, stream>>>(z, att, zg);
    k_transpose<<<dim3(16, 8), 256, 0, stream>>>(outW, 0, outWt, 512, 1024, flag);
    k_gemm<<<dim3(8, 8), 256, 0, stream>>>(zg, 0, nullptr, nullptr, outWt,
                                           hg, 1, outB, flag,
                                           0, nullptr, nullptr, 512, 512, 1024, 0);
    k_transpose<<<dim3(16, 16), 256, 0, stream>>>(projW, 0, projWt, 1024, 1024, flag);
    k_gemm<<<dim3(8, 8), 256, 0, stream>>>(hg, 0, nullptr, nullptr, projWt,
                                           d_out, 3, projB, flag,
                                           0, nullptr, nullptr, 1024, 1024, 1024, 0);
}

// Round 7
// 4425.304 us; speedup vs baseline: 2.8538x; 1.0712x over previous
//
#include <hip/hip_runtime.h>
#include <hip/hip_bf16.h>
#include <stdint.h>

using bf16 = __hip_bfloat16;
typedef __attribute__((ext_vector_type(8))) short short8;
typedef __attribute__((ext_vector_type(4))) float floatx4;

#define N_NODES  32768
#define N_EDGES  131072
#define N_GRAPH  1024
#define NPG      32
#define EPG      128
#define H_DIM    512
#define HE_DIM   128
#define OUT_DIM  1024
#define N_LAYERS 6
#define MC_ROWS  8192

__device__ __forceinline__ float b2f(bf16 v) { return __bfloat162float(v); }
__device__ __forceinline__ bf16  f2b(float f) { return __float2bfloat16(f); }
__device__ __forceinline__ floatx4 mfma16(short8 a, short8 b, floatx4 c) {
    return __builtin_amdgcn_mfma_f32_16x16x32_bf16(a, b, c, 0, 0, 0);
}
__device__ __forceinline__ float ldf(const void* p, size_t i, int isf) {
    return isf ? ((const float*)p)[i] : b2f(((const bf16*)p)[i]);
}
__device__ __forceinline__ void gload_lds16(const void* g, void* l) {
    __builtin_amdgcn_global_load_lds(
        (const __attribute__((address_space(1))) unsigned int*)g,
        (__attribute__((address_space(3))) unsigned int*)l, 16, 0, 0);
}

__device__ const int NODE_OFFS[9] = {0,119,128,139,151,160,165,173,175};

// ---------- dtype detection ----------
__global__ __launch_bounds__(256)
void k_detect(const unsigned short* __restrict__ tab, int n, int* __restrict__ flag)
{
    int big = 0;
    for (int i = threadIdx.x; i < n; i += 256) {
        unsigned short u = tab[i];
        int e = (u >> 7) & 0xFF;
        if (e >= 0x88) big++;
    }
    __shared__ int r[256];
    r[threadIdx.x] = big;
    __syncthreads();
    for (int s = 128; s > 0; s >>= 1) {
        if (threadIdx.x < s) r[threadIdx.x] += r[threadIdx.x + s];
        __syncthreads();
    }
    if (threadIdx.x == 0) *flag = (r[0] > 64) ? 1 : 0;
}

// ---------- per-graph stable counting sort of edges by dst (layer-invariant) ----------
__global__ __launch_bounds__(64)
void k_edge_sort(const int* __restrict__ edge_index, short* __restrict__ sortedE,
                 int* __restrict__ estarts)
{
    const int g = blockIdx.x, t = threadIdx.x;
    __shared__ int d[128];
    __shared__ int off[33];
    d[t]      = edge_index[N_EDGES + g * EPG + t]      - g * NPG;
    d[t + 64] = edge_index[N_EDGES + g * EPG + t + 64] - g * NPG;
    __syncthreads();
    if (t < 32) {
        int c = 0;
        for (int e = 0; e < 128; ++e) c += (d[e] == t) ? 1 : 0;
        off[t + 1] = c;
    }
    __syncthreads();
    if (t == 0) {
        off[0] = 0;
        for (int n = 1; n <= 32; ++n) off[n] += off[n - 1];
    }
    __syncthreads();
    if (t < 33) estarts[g * 33 + t] = off[t];
    if (t < 32) {
        int p = off[t];
        for (int e = 0; e < 128; ++e)
            if (d[e] == t) sortedE[g * EPG + p++] = (short)e;   // stable: increasing e
    }
}

// ---------- transpose W[K][N] (external dtype) -> Wt[N][K] bf16 ----------
__global__ __launch_bounds__(256)
void k_transpose(const void* __restrict__ W, size_t woff, bf16* __restrict__ Wt,
                 int K, int N, const int* __restrict__ flagp)
{
    const int isf = *flagp;
    __shared__ bf16 tile[64][72];
    const int nb = blockIdx.x * 64, kb = blockIdx.y * 64;
    const int t = threadIdx.x;
    const int r = t >> 2, c0 = (t & 3) * 16;
    if (isf) {
        const float* src = (const float*)W + woff + (size_t)(kb + r) * N + nb + c0;
#pragma unroll
        for (int i = 0; i < 16; ++i) tile[r][c0 + i] = f2b(src[i]);
    } else {
        const bf16* src = (const bf16*)W + woff + (size_t)(kb + r) * N + nb + c0;
        *(uint4*)&tile[r][c0]     = ((const uint4*)src)[0];
        *(uint4*)&tile[r][c0 + 8] = ((const uint4*)src)[1];
    }
    __syncthreads();
    __align__(16) bf16 vals[16];
#pragma unroll
    for (int i = 0; i < 16; ++i) vals[i] = tile[c0 + i][r];
    bf16* dst = Wt + (size_t)(nb + r) * K + kb + c0;
    *(uint4*)dst       = *(uint4*)&vals[0];
    *(uint4*)(dst + 8) = *(uint4*)&vals[8];
}

// ---------------- node embedding -> f32 z ----------------
__global__ __launch_bounds__(512)
void k_node_embed(const int* __restrict__ x, const void* __restrict__ tab,
                  float* __restrict__ Z, const int* __restrict__ flagp)
{
    const int isf = *flagp;
    const int n = blockIdx.x, t = threadIdx.x;
    __shared__ int xi[9];
    if (t < 9) xi[t] = NODE_OFFS[t] + x[(size_t)n * 9 + t];
    __syncthreads();
    float s = 0.f;
#pragma unroll
    for (int f = 0; f < 9; ++f) s += ldf(tab, (size_t)xi[f] * H_DIM + t, isf);
    Z[(size_t)n * H_DIM + t] = s;
}

// ------- bond Gram via MFMA: S += E^T E, mu += colsum(E); E recomputed from tables -------
__global__ __launch_bounds__(256)
void k_bond_gram(const int* __restrict__ ea, const void* __restrict__ etab,
                 float* __restrict__ S, float* __restrict__ mu, const int* __restrict__ flagp)
{
    const int isf = *flagp;
    const int tid = threadIdx.x;
    const int lane = tid & 63, wv = tid >> 6, q = lane >> 4, l15 = lane & 15;
    __shared__ __align__(16) bf16 Et[128][136];
    __shared__ int eix[128][3];

    floatx4 acc[2][8];
#pragma unroll
    for (int i = 0; i < 2; ++i)
#pragma unroll
        for (int j = 0; j < 8; ++j) acc[i][j] = (floatx4){0.f,0.f,0.f,0.f};
    float muacc = 0.f;
    const int e0 = blockIdx.x * 512;

    for (int r = 0; r < 4; ++r) {
        __syncthreads();
        if (tid < 128) {
            int e = e0 + r * 128 + tid;
            eix[tid][0] = ea[(size_t)e * 3 + 0];
            eix[tid][1] = 119 + ea[(size_t)e * 3 + 1];
            eix[tid][2] = 128 + ea[(size_t)e * 3 + 2];
        }
        __syncthreads();
        {
            int c = tid & 127, eh = (tid >> 7) * 64;
            for (int e = eh; e < eh + 64; e += 2) {
                float s0 = ldf(etab, (size_t)eix[e][0] * HE_DIM + c, isf)
                         + ldf(etab, (size_t)eix[e][1] * HE_DIM + c, isf)
                         + ldf(etab, (size_t)eix[e][2] * HE_DIM + c, isf);
                float s1 = ldf(etab, (size_t)eix[e+1][0] * HE_DIM + c, isf)
                         + ldf(etab, (size_t)eix[e+1][1] * HE_DIM + c, isf)
                         + ldf(etab, (size_t)eix[e+1][2] * HE_DIM + c, isf);
                bf16 h0 = f2b(s0), h1 = f2b(s1);
                unsigned int pk = (unsigned int)*(unsigned short*)&h0
                                | ((unsigned int)*(unsigned short*)&h1 << 16);
                *(unsigned int*)&Et[c][e] = pk;
                muacc += b2f(h0) + b2f(h1);
            }
        }
        __syncthreads();
#pragma unroll
        for (int kc = 0; kc < 4; ++kc) {
            short8 a0 = *(const short8*)&Et[wv * 32 + l15][kc * 32 + q * 8];
            short8 a1 = *(const short8*)&Et[wv * 32 + 16 + l15][kc * 32 + q * 8];
#pragma unroll
            for (int nt = 0; nt < 8; ++nt) {
                short8 b = *(const short8*)&Et[nt * 16 + l15][kc * 32 + q * 8];
                acc[0][nt] = mfma16(a0, b, acc[0][nt]);
                acc[1][nt] = mfma16(a1, b, acc[1][nt]);
            }
        }
    }
#pragma unroll
    for (int mt = 0; mt < 2; ++mt)
#pragma unroll
        for (int nt = 0; nt < 8; ++nt)
#pragma unroll
            for (int rr = 0; rr < 4; ++rr) {
                int row = wv * 32 + mt * 16 + q * 4 + rr;
                atomicAdd(&S[(size_t)row * 128 + nt * 16 + l15], acc[mt][nt][rr]);
            }
    atomicAdd(&mu[tid & 127], muacc);
}

// ------- per-layer fold: bond BN scale/shift (bias cancels in BN) -------
__global__ __launch_bounds__(128)
void k_bond_fold(const float* __restrict__ S, const float* __restrict__ mu,
                 const bf16* __restrict__ bWt,
                 const void* __restrict__ bG, const void* __restrict__ bBe, size_t go,
                 float* __restrict__ scale1, float* __restrict__ shift1,
                 const int* __restrict__ flagp)
{
    const int isf = *flagp;
    const int j = blockIdx.x;
    const int k = threadIdx.x;
    __shared__ float wbuf[128];
    __shared__ float rp[2][2];
    wbuf[k] = b2f(bWt[(size_t)j * 128 + k]);
    __syncthreads();
    float wk = wbuf[k];
    float dot = 0.f;
    for (int m = 0; m < 128; ++m) dot += S[(size_t)m * 128 + k] * wbuf[m];
    float p1 = wk * dot;
    float p2 = mu[k] * wk;
    for (int off = 32; off > 0; off >>= 1) {
        p1 += __shfl_down(p1, off, 64);
        p2 += __shfl_down(p2, off, 64);
    }
    if ((k & 63) == 0) { rp[k >> 6][0] = p1; rp[k >> 6][1] = p2; }
    __syncthreads();
    if (k == 0) {
        const float invE = 1.f / (float)N_EDGES;
        float mean = (rp[0][1] + rp[1][1]) * invE;
        float var  = (rp[0][0] + rp[1][0]) * invE - mean * mean;
        var = var < 0.f ? 0.f : var;
        float rstd = rsqrtf(var + 1e-5f);
        float sc = ldf(bG, go + j, isf) * rstd;
        scale1[j] = sc;
        shift1[j] = ldf(bBe, go + j, isf) - mean * sc;
    }
}

// --- fused: e recompute; ee=relu(BN(e@bW)); msg=bn2(z)[src]+ee; sorted segment-sum; z=bn2(z)+agg ---
__global__ __launch_bounds__(256)
void k_bond_gemm_agg(const int* __restrict__ ea, const void* __restrict__ etab,
                     const bf16* __restrict__ bWt,
                     const int* __restrict__ edge_index,
                     const short* __restrict__ sortedE, const int* __restrict__ estarts,
                     const float* __restrict__ Z,
                     const float* __restrict__ scale1, const float* __restrict__ shift1,
                     const float* __restrict__ zsc, const float* __restrict__ zsh,
                     float* __restrict__ X2, const int* __restrict__ flagp)
{
    const int isf = *flagp;
    const int tid = threadIdx.x;
    const int lane = tid & 63, wv = tid >> 6, q = lane >> 4, l15 = lane & 15;
    const int nc = blockIdx.x;
    const int g  = blockIdx.y;

    __shared__ __align__(16) char smem[54784];
    bf16 (*As)[136] = (bf16(*)[136])smem;
    bf16 (*Bs)[136] = (bf16(*)[136])(smem + 34816);
    float (*Cs)[68] = (float(*)[68])smem;
    int*   srcl = (int*)(smem + 52224);          // 512 B
    short* sid  = (short*)(smem + 52736);        // 256 B (sorted local edge ids)
    int*   sst  = (int*)(smem + 52992);          // 132 B (segment starts, 33)
    int (*eix)[3] = (int(*)[3])(smem + 53248);   // 1536 B

    if (tid < 128) {
        int e = g * EPG + tid;
        srcl[tid] = edge_index[e];
        sid[tid]  = sortedE[g * EPG + tid];
        eix[tid][0] = ea[(size_t)e * 3 + 0];
        eix[tid][1] = 119 + ea[(size_t)e * 3 + 1];
        eix[tid][2] = 128 + ea[(size_t)e * 3 + 2];
    }
    if (tid >= 128 && tid < 161) sst[tid - 128] = estarts[g * 33 + (tid - 128)];
    __syncthreads();
    {   // stage A: recompute edge embedding, 2 threads per row
        int row = tid >> 1, half = (tid & 1) * 64;
        int eb[3] = {eix[row][0], eix[row][1], eix[row][2]};
#pragma unroll
        for (int seg = 0; seg < 4; ++seg) {
            float a16[16];
#pragma unroll
            for (int j = 0; j < 16; ++j) a16[j] = 0.f;
#pragma unroll
            for (int f = 0; f < 3; ++f) {
                size_t base = (size_t)eb[f] * HE_DIM + half + seg * 16;
                if (isf) {
                    const float4* s = (const float4*)((const float*)etab + base);
#pragma unroll
                    for (int v = 0; v < 4; ++v) {
                        float4 t = s[v];
                        a16[v*4+0] += t.x; a16[v*4+1] += t.y;
                        a16[v*4+2] += t.z; a16[v*4+3] += t.w;
                    }
                } else {
                    const bf16* s = (const bf16*)etab + base;
#pragma unroll
                    for (int j = 0; j < 16; ++j) a16[j] += b2f(s[j]);
                }
            }
#pragma unroll
            for (int j = 0; j < 16; ++j) As[row][half + seg * 16 + j] = f2b(a16[j]);
        }
    }
    {   // stage B^T from bWt [512][128]
        int row = tid >> 2, seg = (tid & 3) * 32;
        const bf16* src = bWt + (size_t)(nc * 64 + row) * 128 + seg;
        uint4 v0 = ((const uint4*)src)[0];
        uint4 v1 = ((const uint4*)src)[1];
        uint4 v2 = ((const uint4*)src)[2];
        uint4 v3 = ((const uint4*)src)[3];
        *(uint4*)(&Bs[row][seg +  0]) = v0;
        *(uint4*)(&Bs[row][seg +  8]) = v1;
        *(uint4*)(&Bs[row][seg + 16]) = v2;
        *(uint4*)(&Bs[row][seg + 24]) = v3;
    }
    __syncthreads();

    floatx4 acc[2][4];
#pragma unroll
    for (int i = 0; i < 2; ++i)
#pragma unroll
        for (int jj = 0; jj < 4; ++jj) acc[i][jj] = (floatx4){0.f,0.f,0.f,0.f};
    const int m0 = wv * 32;
#pragma unroll
    for (int kk = 0; kk < 4; ++kk) {
        int k0 = kk * 32;
        short8 a0 = *(const short8*)(&As[m0 + l15][k0 + q * 8]);
        short8 a1 = *(const short8*)(&As[m0 + 16 + l15][k0 + q * 8]);
#pragma unroll
        for (int nt = 0; nt < 4; ++nt) {
            short8 bfr = *(const short8*)(&Bs[nt * 16 + l15][k0 + q * 8]);
            acc[0][nt] = mfma16(a0, bfr, acc[0][nt]);
            acc[1][nt] = mfma16(a1, bfr, acc[1][nt]);
        }
    }
    __syncthreads();
#pragma unroll
    for (int mt = 0; mt < 2; ++mt)
#pragma unroll
        for (int nt = 0; nt < 4; ++nt)
#pragma unroll
            for (int r = 0; r < 4; ++r)
                Cs[m0 + mt * 16 + q * 4 + r][nt * 16 + l15] = acc[mt][nt][r];
    __syncthreads();
    {   // phase A: bond-BN + relu + bn2(z)[src] gather
        int j = tid & 63, eg = (tid >> 6) * 32;
        int col = nc * 64 + j;
        float sc = scale1[col], sh = shift1[col];
        float zs = zsc ? zsc[col] : 1.f, zh = zsc ? zsh[col] : 0.f;
#pragma unroll 4
        for (int e = eg; e < eg + 32; ++e) {
            float y = Cs[e][j] * sc + sh;
            y = y > 0.f ? y : 0.f;
            float zv = Z[(size_t)srcl[e] * H_DIM + col];
            if (zsc) { zv = zv * zs + zh; zv = zv > 0.f ? zv : 0.f; }
            Cs[e][j] = y + zv;
        }
    }
    __syncthreads();
    {   // phase B: sorted segment-sum by dst (stable order == increasing original e)
        int j = tid & 63, base = (tid >> 6) * 8;
        int col = nc * 64 + j;
        float zs = zsc ? zsc[col] : 1.f, zh = zsc ? zsh[col] : 0.f;
#pragma unroll
        for (int r = 0; r < 8; ++r) {
            int n = base + r;
            int s0 = sst[n], s1 = sst[n + 1];   // wave-uniform bounds
            float a = 0.f;
            for (int idx = s0; idx < s1; ++idx)
                a += Cs[sid[idx]][j];
            size_t zi = (size_t)(g * NPG + n) * H_DIM + col;
            float zv = Z[zi];
            if (zsc) { zv = zv * zs + zh; zv = zv > 0.f ? zv : 0.f; }
            X2[zi] = a + zv;
        }
    }
}

// ---- fast GEMM: C[128x128 tiles] = A[M,K] @ Bt^T, Bt pre-transposed [N][K] bf16 ----
__global__ __launch_bounds__(256, 2)
void k_gemm(const void* __restrict__ Av, int aMode,
            const float* __restrict__ bnsc, const float* __restrict__ bnsh,
            const bf16* __restrict__ Bt,
            void* __restrict__ Cv, int cMode,
            const void* __restrict__ bias, const int* __restrict__ flagp,
            int statsMode, float* __restrict__ cs, float* __restrict__ cq,
            int K, int lda, int ldc, int mStoreMin)
{
    const int tid  = threadIdx.x;
    const int lane = tid & 63;
    const int wv   = tid >> 6;
    const int q    = lane >> 4;
    const int l15  = lane & 15;
    const int wm   = wv & 1;
    const int wn   = wv >> 1;
    const int m0   = blockIdx.y * 128;
    const int n0   = blockIdx.x * 128;

    __shared__ __align__(16) bf16 As[128][40];
    __shared__ __align__(16) bf16 Bs[128][32];

    floatx4 acc[4][4];
#pragma unroll
    for (int mt = 0; mt < 4; ++mt)
#pragma unroll
        for (int nt = 0; nt < 4; ++nt) acc[mt][nt] = (floatx4){0.f,0.f,0.f,0.f};

    const int ar = tid >> 1;
    const int ak = (tid & 1) * 16;
    const bf16* BtBase = Bt + (size_t)n0 * K;
    const int cb0 = wv * 64;
    const int cb1 = (4 + wv) * 64;

    for (int k0 = 0; k0 < K; k0 += 32) {
        short av[16];
        if (aMode == 1) {
            const float* Ap = (const float*)Av + (size_t)(m0 + ar) * lda + k0 + ak;
#pragma unroll
            for (int i = 0; i < 16; i += 4) {
                float4 f = *(const float4*)(Ap + i);
                bf16 h0 = f2b(f.x), h1 = f2b(f.y), h2 = f2b(f.z), h3 = f2b(f.w);
                av[i] = *(short*)&h0; av[i+1] = *(short*)&h1;
                av[i+2] = *(short*)&h2; av[i+3] = *(short*)&h3;
            }
        } else {
            const bf16* Ap = (const bf16*)Av + (size_t)(m0 + ar) * lda + k0 + ak;
            *(uint4*)&av[0] = *(const uint4*)Ap;
            *(uint4*)&av[8] = *(const uint4*)(Ap + 8);
            if (aMode == 2) {
#pragma unroll
                for (int i = 0; i < 16; ++i) {
                    bf16 h = *(bf16*)&av[i];
                    float f = b2f(h) * bnsc[k0 + ak + i] + bnsh[k0 + ak + i];
                    f = f > 0.f ? f : 0.f;
                    bf16 o = f2b(f);
                    av[i] = *(short*)&o;
                }
            }
        }
        __syncthreads();
        {
            int c0i = cb0 + lane;
            gload_lds16(BtBase + (size_t)(c0i >> 2) * K + k0 + (c0i & 3) * 8,
                        &Bs[0][0] + (size_t)cb0 * 8);
            int c1i = cb1 + lane;
            gload_lds16(BtBase + (size_t)(c1i >> 2) * K + k0 + (c1i & 3) * 8,
                        &Bs[0][0] + (size_t)cb1 * 8);
        }
        *(uint4*)(&As[ar][ak])     = *(uint4*)&av[0];
        *(uint4*)(&As[ar][ak + 8]) = *(uint4*)&av[8];
        __syncthreads();
        short8 af[4], bfr[4];
#pragma unroll
        for (int mt = 0; mt < 4; ++mt)
            af[mt] = *(const short8*)(&As[wm * 64 + mt * 16 + l15][q * 8]);
#pragma unroll
        for (int nt = 0; nt < 4; ++nt)
            bfr[nt] = *(const short8*)(&Bs[wn * 64 + nt * 16 + l15][q * 8]);
#pragma unroll
        for (int mt = 0; mt < 4; ++mt)
#pragma unroll
            for (int nt = 0; nt < 4; ++nt)
                acc[mt][nt] = mfma16(af[mt], bfr[nt], acc[mt][nt]);
    }

    const int isf = flagp ? *flagp : 0;
    int cm = cMode;
    if (cMode == 3) cm = isf ? 2 : 1;
    float bvv[4] = {0.f, 0.f, 0.f, 0.f};
    if (bias) {
#pragma unroll
        for (int nt = 0; nt < 4; ++nt)
            bvv[nt] = ldf(bias, (size_t)n0 + wn * 64 + nt * 16 + l15, isf);
    }
    if (cm) {
#pragma unroll
        for (int mt = 0; mt < 4; ++mt)
#pragma unroll
            for (int r = 0; r < 4; ++r) {
                int row = m0 + wm * 64 + mt * 16 + q * 4 + r;
                if (row < mStoreMin) continue;
                size_t crow = (size_t)(row - mStoreMin) * ldc + n0;
                if (cm == 2) {
                    float* Crow = (float*)Cv + crow;
#pragma unroll
                    for (int nt = 0; nt < 4; ++nt)
                        Crow[wn * 64 + nt * 16 + l15] = acc[mt][nt][r] + bvv[nt];
                } else {
                    bf16* Crow = (bf16*)Cv + crow;
#pragma unroll
                    for (int nt = 0; nt < 4; ++nt)
                        Crow[wn * 64 + nt * 16 + l15] = f2b(acc[mt][nt][r] + bvv[nt]);
                }
            }
    }
    if (statsMode) {
        float ls[4], lq[4];
#pragma unroll
        for (int nt = 0; nt < 4; ++nt) { ls[nt] = 0.f; lq[nt] = 0.f; }
#pragma unroll
        for (int nt = 0; nt < 4; ++nt)
#pragma unroll
            for (int mt = 0; mt < 4; ++mt)
#pragma unroll
                for (int r = 0; r < 4; ++r) {
                    float v = acc[mt][nt][r];
                    if (statsMode == 1) v = b2f(f2b(v));
                    ls[nt] += v; lq[nt] += v * v;
                }
        float* red = (float*)&As[0][0];
        __syncthreads();
        red[tid] = 0.f;
        __syncthreads();
#pragma unroll
        for (int nt = 0; nt < 4; ++nt) {
            int col = wn * 64 + nt * 16 + l15;
            atomicAdd(&red[col * 2],     ls[nt]);
            atomicAdd(&red[col * 2 + 1], lq[nt]);
        }
        __syncthreads();
        if (tid < 128) {
            atomicAdd(&cs[n0 + tid], red[tid * 2]);
            atomicAdd(&cq[n0 + tid], red[tid * 2 + 1]);
        }
    }
}

__global__ __launch_bounds__(256)
void k_bn_finalize(const float* __restrict__ cs, const float* __restrict__ cq,
                   const void* __restrict__ g, const void* __restrict__ be, size_t goff,
                   int cols, float invR, float* __restrict__ scale, float* __restrict__ shift,
                   const int* __restrict__ flagp)
{
    const int isf = *flagp;
    int c = blockIdx.x * 256 + threadIdx.x;
    if (c < cols) {
        float mean = cs[c] * invR;
        float var = cq[c] * invR - mean * mean;
        var = var < 0.f ? 0.f : var;
        float rstd = rsqrtf(var + 1e-5f);
        float sc = ldf(g, goff + c, isf) * rstd;
        scale[c] = sc;
        shift[c] = ldf(be, goff + c, isf) - mean * sc;
    }
}

__global__ __launch_bounds__(256)
void k_bn_apply_relu_f32(float* __restrict__ X, const float* __restrict__ scale,
                         const float* __restrict__ shift, int colmask, unsigned int nvec4)
{
    unsigned int i = blockIdx.x * 256 + threadIdx.x;
    if (i >= nvec4) return;
    float4* p = (float4*)X + i;
    int cbase = (int)(((size_t)i * 4) & (size_t)colmask);
    float4 v = *p;
    float f;
    f = v.x * scale[cbase+0] + shift[cbase+0]; v.x = f > 0.f ? f : 0.f;
    f = v.y * scale[cbase+1] + shift[cbase+1]; v.y = f > 0.f ? f : 0.f;
    f = v.z * scale[cbase+2] + shift[cbase+2]; v.z = f > 0.f ? f : 0.f;
    f = v.w * scale[cbase+3] + shift[cbase+3]; v.w = f > 0.f ? f : 0.f;
    *p = v;
}

// ---------------- attention tail ----------------
__global__ __launch_bounds__(256)
void k_att_v(const void* __restrict__ gapW, const void* __restrict__ gapB,
             const void* __restrict__ attW, const void* __restrict__ attB,
             float* __restrict__ v, const int* __restrict__ flagp)
{
    const int isf = *flagp;
    const int lane = threadIdx.x & 63, wv = threadIdx.x >> 6;
    if (blockIdx.x == 256) {
        if (wv == 0) {
            float s = 0.f;
            for (int k = lane; k < 512; k += 64) s += ldf(gapB, k, isf) * ldf(attW, k, isf);
            for (int off = 32; off > 0; off >>= 1) s += __shfl_down(s, off, 64);
            if (lane == 0) v[1024] = s + ldf(attB, 0, isf);
        }
        return;
    }
    const int o = blockIdx.x * 4 + wv;
    float s = 0.f;
    for (int k = lane; k < 512; k += 64) s += ldf(gapW, (size_t)o * 512 + k, isf) * ldf(attW, k, isf);
    for (int off = 32; off > 0; off >>= 1) s += __shfl_down(s, off, 64);
    if (lane == 0) v[o] = s;
}

__global__ __launch_bounds__(256)
void k_qv(const void* __restrict__ outW, const void* __restrict__ outB,
          const float* __restrict__ v, float* __restrict__ qv, const int* __restrict__ flagp)
{
    const int isf = *flagp;
    const int lane = threadIdx.x & 63, wv = threadIdx.x >> 6;
    if (blockIdx.x == 128) {
        if (wv == 0) {
            float s = 0.f;
            for (int o = lane; o < 1024; o += 64) s += ldf(outB, o, isf) * v[o];
            for (int off = 32; off > 0; off >>= 1) s += __shfl_down(s, off, 64);
            if (lane == 0) qv[512] = s + v[1024];
        }
        return;
    }
    const int k = blockIdx.x * 4 + wv;
    float s = 0.f;
    for (int o = lane; o < 1024; o += 64) s += ldf(outW, (size_t)k * 1024 + o, isf) * v[o];
    for (int off = 32; off > 0; off >>= 1) s += __shfl_down(s, off, 64);
    if (lane == 0) qv[k] = s;
}

__global__ __launch_bounds__(256)
void k_att_dot(const float* __restrict__ Z, const float* __restrict__ qv, float* __restrict__ att)
{
    const int lane = threadIdx.x & 63, wv = threadIdx.x >> 6;
    const int row = blockIdx.x * 4 + wv;
    const float* p = Z + (size_t)row * 512 + lane * 8;
    float s = 0.f;
#pragma unroll
    for (int i = 0; i < 8; ++i) s += p[i] * qv[lane * 8 + i];
    for (int off = 32; off > 0; off >>= 1) s += __shfl_down(s, off, 64);
    if (lane == 0) att[row] = s + qv[512];
}

__global__ __launch_bounds__(256)
void k_softmax_pool(const float* __restrict__ Z, const float* __restrict__ att, bf16* __restrict__ ZG)
{
    const int g = blockIdx.x, t = threadIdx.x;
    __shared__ float alpha[32];
    if (t < 32) alpha[t] = att[g * 32 + t];
    __syncthreads();
    if (t == 0) {
        float mx = alpha[0];
        for (int p = 1; p < 32; ++p) mx = fmaxf(mx, alpha[p]);
        float sum = 0.f;
        for (int p = 0; p < 32; ++p) { float e = __expf(alpha[p] - mx); alpha[p] = e; sum += e; }
        float inv = 1.f / sum;
        for (int p = 0; p < 32; ++p) alpha[p] *= inv;
    }
    __syncthreads();
#pragma unroll
    for (int ci = 0; ci < 2; ++ci) {
        int c = t + ci * 256;
        float acc = 0.f;
        for (int p = 0; p < 32; ++p)
            acc += alpha[p] * Z[(size_t)(g * 32 + p) * 512 + c];
        ZG[(size_t)g * 512 + c] = f2b(acc);
    }
}

// ---------------- launcher ----------------
extern "C" void kernel_launch(void* const* d_in, const int* in_sizes, int n_in,
                              void* d_out, int out_size, void* d_ws, size_t ws_size,
                              hipStream_t stream)
{
    (void)in_sizes; (void)n_in; (void)out_size; (void)ws_size;
    const int*  x          = (const int*)d_in[0];
    const int*  edge_attr  = (const int*)d_in[1];
    const int*  edge_index = (const int*)d_in[2];
    const void* node_tab   = d_in[4];
    const void* edge_tab   = d_in[5];
    const void* bondW      = d_in[6];
    const void* bondG      = d_in[8];
    const void* bondBeta   = d_in[9];
    const void* atomW1     = d_in[10];
    const void* atomG      = d_in[12];
    const void* atomBeta   = d_in[13];
    const void* atomW2     = d_in[14];
    const void* normG      = d_in[16];
    const void* normB      = d_in[17];
    const void* outW       = d_in[18];
    const void* outB       = d_in[19];
    const void* gapW       = d_in[20];
    const void* gapB       = d_in[21];
    const void* attW       = d_in[22];
    const void* attB       = d_in[23];
    const void* projW      = d_in[24];
    const void* projB      = d_in[25];

    char* ws = (char*)d_ws;
    float* z      = (float*)ws;                              // 64 MB
    bf16*  Uc     = (bf16*)(ws + 67108864ull);               // 16 MB
    bf16*  zg     = Uc;
    bf16*  hg     = (bf16*)(ws + 67108864ull + 1048576ull);
    bf16*  projWt = (bf16*)(ws + 67108864ull + 4194304ull);
    bf16*  W1t    = (bf16*)(ws + 83886080ull);               // 1 MB
    bf16*  W2t    = (bf16*)(ws + 84934656ull);               // 1 MB
    bf16*  bWt    = (bf16*)(ws + 85983232ull);               // 128 KB
    bf16*  outWt  = W1t;
    char*  st  = ws + 86114304ull;
    int*   flag = (int*)(st);
    float* S    = (float*)(st + 256);       // 64 KB
    float* mu   = (float*)(st + 65792);     // 512 B
    float* cs   = (float*)(st + 66304);     // 4 KB
    float* cq   = (float*)(st + 70400);     // 4 KB
    float* cs2  = (float*)(st + 74496);     // 2 KB
    float* cq2  = (float*)(st + 76544);     // 2 KB
    float* sc1  = (float*)(st + 78592);     // 4 KB
    float* sh1  = (float*)(st + 82688);     // 4 KB
    float* sc2  = (float*)(st + 86784);     // 2 KB
    float* sh2  = (float*)(st + 88832);     // 2 KB
    float* vv   = (float*)(st + 90880);
    float* qv   = (float*)(st + 95232);
    float* att  = (float*)(st + 97536);     // 128 KB
    short* sortedE = (short*)(st + 228608); // 256 KB
    int*   estarts = (int*)(st + 490752);   // 132 KB  (end: st+625920 < ws+87,253,504)

    k_detect<<<1, 256, 0, stream>>>((const unsigned short*)node_tab, 4096, flag);
    k_edge_sort<<<N_GRAPH, 64, 0, stream>>>(edge_index, sortedE, estarts);
    hipMemsetAsync(st + 256, 0, 66048, stream);   // S + mu
    k_bond_gram<<<256, 256, 0, stream>>>(edge_attr, edge_tab, S, mu, flag);
    k_node_embed<<<N_NODES, 512, 0, stream>>>(x, node_tab, z, flag);

    for (int l = 0; l < N_LAYERS; ++l) {
        const float* zscp = (l == 0) ? nullptr : sc2;
        const float* zshp = (l == 0) ? nullptr : sh2;

        k_transpose<<<dim3(16, 8), 256, 0, stream>>>(atomW1, (size_t)l * 512 * 1024, W1t, 512, 1024, flag);
        k_transpose<<<dim3(8, 16), 256, 0, stream>>>(atomW2, (size_t)l * 1024 * 512, W2t, 1024, 512, flag);
        k_transpose<<<dim3(8, 2), 256, 0, stream>>>(bondW, (size_t)l * 128 * 512, bWt, 128, 512, flag);

        k_bond_fold<<<512, 128, 0, stream>>>(S, mu, bWt, bondG, bondBeta, (size_t)l * 512, sc1, sh1, flag);
        k_bond_gemm_agg<<<dim3(8, N_GRAPH), 256, 0, stream>>>(edge_attr, edge_tab, bWt,
                                                              edge_index, sortedE, estarts,
                                                              z, sc1, sh1, zscp, zshp, z, flag);

        hipMemsetAsync(cs, 0, 12288, stream);  // cs, cq, cs2, cq2
        k_gemm<<<dim3(8, 256), 256, 0, stream>>>(z, 1, nullptr, nullptr, W1t,
                                                 Uc, 1, nullptr, nullptr,
                                                 1, cs, cq, 512, 512, 1024, 24576);
        k_bn_finalize<<<4, 256, 0, stream>>>(cs, cq, atomG, atomBeta, (size_t)l * 1024,
                                             1024, 1.f / 32768.f, sc1, sh1, flag);
        for (int mi = 0; mi < 4; ++mi) {
            int mc = (mi + 3) & 3;
            float* zc = z + (size_t)mc * MC_ROWS * 512;
            if (mc != 3)
                k_gemm<<<dim3(8, 64), 256, 0, stream>>>(zc, 1, nullptr, nullptr, W1t,
                                                        Uc, 1, nullptr, nullptr,
                                                        0, nullptr, nullptr, 512, 512, 1024, 0);
            k_gemm<<<dim3(4, 64), 256, 0, stream>>>(Uc, 2, sc1, sh1, W2t,
                                                    zc, 2, nullptr, nullptr,
                                                    2, cs2, cq2, 1024, 1024, 512, 0);
        }
        k_bn_finalize<<<2, 256, 0, stream>>>(cs2, cq2, normG, normB, (size_t)l * 512,
                                             512, 1.f / 32768.f, sc2, sh2, flag);
    }
    k_bn_apply_relu_f32<<<16384, 256, 0, stream>>>(z, sc2, sh2, 511, 4194304u);

    k_att_v<<<257, 256, 0, stream>>>(gapW, gapB, attW, attB, vv, flag);
    k_qv<<<129, 256, 0, stream>>>(outW, outB, vv, qv, flag);
    k_att_dot<<<8192, 256, 0, stream>>>(z, qv, att);
    k_softmax_pool<<<N_GRAPH, 256, 0, stream>>>(z, att, zg);
    k_transpose<<<dim3(16, 8), 256, 0, stream>>>(outW, 0, outWt, 512, 1024, flag);
    k_gemm<<<dim3(8, 8), 256, 0, stream>>>(zg, 0, nullptr, nullptr, outWt,
                                           hg, 1, outB, flag,
                                           0, nullptr, nullptr, 512, 512, 1024, 0);
    k_transpose<<<dim3(16, 16), 256, 0, stream>>>(projW, 0, projWt, 1024, 1024, flag);
    k_gemm<<<dim3(8, 8), 256, 0, stream>>>(hg, 0, nullptr, nullptr, projWt,
                                           d_out, 3, projB, flag,
                                           0, nullptr, nullptr, 1024, 1024, 1024, 0);
}

// Round 8
// 3620.630 us; speedup vs baseline: 3.4880x; 1.2222x over previous
//
#include <hip/hip_runtime.h>
#include <hip/hip_bf16.h>
#include <stdint.h>

using bf16 = __hip_bfloat16;
typedef __attribute__((ext_vector_type(8))) short short8;
typedef __attribute__((ext_vector_type(4))) float floatx4;

#define N_NODES  32768
#define N_EDGES  131072
#define N_GRAPH  1024
#define NPG      32
#define EPG      128
#define H_DIM    512
#define HE_DIM   128
#define OUT_DIM  1024
#define N_LAYERS 6
#define MC_ROWS  8192

__device__ __forceinline__ float b2f(bf16 v) { return __bfloat162float(v); }
__device__ __forceinline__ bf16  f2b(float f) { return __float2bfloat16(f); }
__device__ __forceinline__ floatx4 mfma16(short8 a, short8 b, floatx4 c) {
    return __builtin_amdgcn_mfma_f32_16x16x32_bf16(a, b, c, 0, 0, 0);
}
__device__ __forceinline__ float ldf(const void* p, size_t i, int isf) {
    return isf ? ((const float*)p)[i] : b2f(((const bf16*)p)[i]);
}
__device__ __forceinline__ void gload_lds16(const void* g, void* l) {
    __builtin_amdgcn_global_load_lds(
        (const __attribute__((address_space(1))) unsigned int*)g,
        (__attribute__((address_space(3))) unsigned int*)l, 16, 0, 0);
}

__device__ const int NODE_OFFS[9] = {0,119,128,139,151,160,165,173,175};

// ---------- dtype detection ----------
__global__ __launch_bounds__(256)
void k_detect(const unsigned short* __restrict__ tab, int n, int* __restrict__ flag)
{
    int big = 0;
    for (int i = threadIdx.x; i < n; i += 256) {
        unsigned short u = tab[i];
        int e = (u >> 7) & 0xFF;
        if (e >= 0x88) big++;
    }
    __shared__ int r[256];
    r[threadIdx.x] = big;
    __syncthreads();
    for (int s = 128; s > 0; s >>= 1) {
        if (threadIdx.x < s) r[threadIdx.x] += r[threadIdx.x + s];
        __syncthreads();
    }
    if (threadIdx.x == 0) *flag = (r[0] > 64) ? 1 : 0;
}

// ---------- per-graph stable counting sort of edges by dst (layer-invariant) ----------
__global__ __launch_bounds__(64)
void k_edge_sort(const int* __restrict__ edge_index, short* __restrict__ sortedE,
                 int* __restrict__ estarts)
{
    const int g = blockIdx.x, t = threadIdx.x;
    __shared__ int d[128];
    __shared__ int off[33];
    d[t]      = edge_index[N_EDGES + g * EPG + t]      - g * NPG;
    d[t + 64] = edge_index[N_EDGES + g * EPG + t + 64] - g * NPG;
    __syncthreads();
    if (t < 32) {
        int c = 0;
        for (int e = 0; e < 128; ++e) c += (d[e] == t) ? 1 : 0;
        off[t + 1] = c;
    }
    __syncthreads();
    if (t == 0) {
        off[0] = 0;
        for (int n = 1; n <= 32; ++n) off[n] += off[n - 1];
    }
    __syncthreads();
    if (t < 33) estarts[g * 33 + t] = off[t];
    if (t < 32) {
        int p = off[t];
        for (int e = 0; e < 128; ++e)
            if (d[e] == t) sortedE[g * EPG + p++] = (short)e;   // stable: increasing e
    }
}

// ---------- optional: materialize edge embedding (order-matched to recompute) ----------
__global__ __launch_bounds__(512)
void k_edge_embed(const int* __restrict__ ea, const void* __restrict__ etab,
                  bf16* __restrict__ Ebf, const int* __restrict__ flagp)
{
    const int isf = *flagp;
    const int t = threadIdx.x;
    const int sub = t >> 7, c = t & 127;
    const int e = blockIdx.x * 4 + sub;
    size_t eb = (size_t)e * 3;
    int i0 = ea[eb], i1 = 119 + ea[eb + 1], i2 = 128 + ea[eb + 2];
    float s = ldf(etab, (size_t)i0 * HE_DIM + c, isf);
    s += ldf(etab, (size_t)i1 * HE_DIM + c, isf);
    s += ldf(etab, (size_t)i2 * HE_DIM + c, isf);
    Ebf[(size_t)e * HE_DIM + c] = f2b(s);
}

// ---------- transpose W[K][N] (external dtype) -> Wt[N][K] bf16 ----------
__global__ __launch_bounds__(256)
void k_transpose(const void* __restrict__ W, size_t woff, bf16* __restrict__ Wt,
                 int K, int N, const int* __restrict__ flagp)
{
    const int isf = *flagp;
    __shared__ bf16 tile[64][72];
    const int nb = blockIdx.x * 64, kb = blockIdx.y * 64;
    const int t = threadIdx.x;
    const int r = t >> 2, c0 = (t & 3) * 16;
    if (isf) {
        const float* src = (const float*)W + woff + (size_t)(kb + r) * N + nb + c0;
#pragma unroll
        for (int i = 0; i < 16; ++i) tile[r][c0 + i] = f2b(src[i]);
    } else {
        const bf16* src = (const bf16*)W + woff + (size_t)(kb + r) * N + nb + c0;
        *(uint4*)&tile[r][c0]     = ((const uint4*)src)[0];
        *(uint4*)&tile[r][c0 + 8] = ((const uint4*)src)[1];
    }
    __syncthreads();
    __align__(16) bf16 vals[16];
#pragma unroll
    for (int i = 0; i < 16; ++i) vals[i] = tile[c0 + i][r];
    bf16* dst = Wt + (size_t)(nb + r) * K + kb + c0;
    *(uint4*)dst       = *(uint4*)&vals[0];
    *(uint4*)(dst + 8) = *(uint4*)&vals[8];
}

// ---------------- node embedding -> f32 z ----------------
__global__ __launch_bounds__(512)
void k_node_embed(const int* __restrict__ x, const void* __restrict__ tab,
                  float* __restrict__ Z, const int* __restrict__ flagp)
{
    const int isf = *flagp;
    const int n = blockIdx.x, t = threadIdx.x;
    __shared__ int xi[9];
    if (t < 9) xi[t] = NODE_OFFS[t] + x[(size_t)n * 9 + t];
    __syncthreads();
    float s = 0.f;
#pragma unroll
    for (int f = 0; f < 9; ++f) s += ldf(tab, (size_t)xi[f] * H_DIM + t, isf);
    Z[(size_t)n * H_DIM + t] = s;
}

// ------- bond Gram via MFMA: S += E^T E, mu += colsum(E) -------
__global__ __launch_bounds__(256)
void k_bond_gram(const int* __restrict__ ea, const void* __restrict__ etab,
                 float* __restrict__ S, float* __restrict__ mu, const int* __restrict__ flagp)
{
    const int isf = *flagp;
    const int tid = threadIdx.x;
    const int lane = tid & 63, wv = tid >> 6, q = lane >> 4, l15 = lane & 15;
    __shared__ __align__(16) bf16 Et[128][136];
    __shared__ int eix[128][3];

    floatx4 acc[2][8];
#pragma unroll
    for (int i = 0; i < 2; ++i)
#pragma unroll
        for (int j = 0; j < 8; ++j) acc[i][j] = (floatx4){0.f,0.f,0.f,0.f};
    float muacc = 0.f;
    const int e0 = blockIdx.x * 512;

    for (int r = 0; r < 4; ++r) {
        __syncthreads();
        if (tid < 128) {
            int e = e0 + r * 128 + tid;
            eix[tid][0] = ea[(size_t)e * 3 + 0];
            eix[tid][1] = 119 + ea[(size_t)e * 3 + 1];
            eix[tid][2] = 128 + ea[(size_t)e * 3 + 2];
        }
        __syncthreads();
        {
            int c = tid & 127, eh = (tid >> 7) * 64;
            for (int e = eh; e < eh + 64; e += 2) {
                float s0 = ldf(etab, (size_t)eix[e][0] * HE_DIM + c, isf)
                         + ldf(etab, (size_t)eix[e][1] * HE_DIM + c, isf)
                         + ldf(etab, (size_t)eix[e][2] * HE_DIM + c, isf);
                float s1 = ldf(etab, (size_t)eix[e+1][0] * HE_DIM + c, isf)
                         + ldf(etab, (size_t)eix[e+1][1] * HE_DIM + c, isf)
                         + ldf(etab, (size_t)eix[e+1][2] * HE_DIM + c, isf);
                bf16 h0 = f2b(s0), h1 = f2b(s1);
                unsigned int pk = (unsigned int)*(unsigned short*)&h0
                                | ((unsigned int)*(unsigned short*)&h1 << 16);
                *(unsigned int*)&Et[c][e] = pk;
                muacc += b2f(h0) + b2f(h1);
            }
        }
        __syncthreads();
#pragma unroll
        for (int kc = 0; kc < 4; ++kc) {
            short8 a0 = *(const short8*)&Et[wv * 32 + l15][kc * 32 + q * 8];
            short8 a1 = *(const short8*)&Et[wv * 32 + 16 + l15][kc * 32 + q * 8];
#pragma unroll
            for (int nt = 0; nt < 8; ++nt) {
                short8 b = *(const short8*)&Et[nt * 16 + l15][kc * 32 + q * 8];
                acc[0][nt] = mfma16(a0, b, acc[0][nt]);
                acc[1][nt] = mfma16(a1, b, acc[1][nt]);
            }
        }
    }
#pragma unroll
    for (int mt = 0; mt < 2; ++mt)
#pragma unroll
        for (int nt = 0; nt < 8; ++nt)
#pragma unroll
            for (int rr = 0; rr < 4; ++rr) {
                int row = wv * 32 + mt * 16 + q * 4 + rr;
                atomicAdd(&S[(size_t)row * 128 + nt * 16 + l15], acc[mt][nt][rr]);
            }
    atomicAdd(&mu[tid & 127], muacc);
}

// ------- per-layer fold: bond BN scale/shift (bias cancels in BN) -------
__global__ __launch_bounds__(128)
void k_bond_fold(const float* __restrict__ S, const float* __restrict__ mu,
                 const bf16* __restrict__ bWt,
                 const void* __restrict__ bG, const void* __restrict__ bBe, size_t go,
                 float* __restrict__ scale1, float* __restrict__ shift1,
                 const int* __restrict__ flagp)
{
    const int isf = *flagp;
    const int j = blockIdx.x;
    const int k = threadIdx.x;
    __shared__ float wbuf[128];
    __shared__ float rp[2][2];
    wbuf[k] = b2f(bWt[(size_t)j * 128 + k]);
    __syncthreads();
    float wk = wbuf[k];
    float dot = 0.f;
    for (int m = 0; m < 128; ++m) dot += S[(size_t)m * 128 + k] * wbuf[m];
    float p1 = wk * dot;
    float p2 = mu[k] * wk;
    for (int off = 32; off > 0; off >>= 1) {
        p1 += __shfl_down(p1, off, 64);
        p2 += __shfl_down(p2, off, 64);
    }
    if ((k & 63) == 0) { rp[k >> 6][0] = p1; rp[k >> 6][1] = p2; }
    __syncthreads();
    if (k == 0) {
        const float invE = 1.f / (float)N_EDGES;
        float mean = (rp[0][1] + rp[1][1]) * invE;
        float var  = (rp[0][0] + rp[1][0]) * invE - mean * mean;
        var = var < 0.f ? 0.f : var;
        float rstd = rsqrtf(var + 1e-5f);
        float sc = ldf(bG, go + j, isf) * rstd;
        scale1[j] = sc;
        shift1[j] = ldf(bBe, go + j, isf) - mean * sc;
    }
}

// --- fused bond: GEMM + BN + relu + msg + sorted segment-sum; sorted-C layout ---
__global__ __launch_bounds__(256)
void k_bond_gemm_agg(const int* __restrict__ ea, const void* __restrict__ etab,
                     const bf16* __restrict__ Ebf,        // nullptr -> recompute
                     const bf16* __restrict__ bWt,
                     const int* __restrict__ edge_index,
                     const short* __restrict__ sortedE, const int* __restrict__ estarts,
                     const float* __restrict__ Z,
                     const float* __restrict__ scale1, const float* __restrict__ shift1,
                     const float* __restrict__ zsc, const float* __restrict__ zsh,
                     float* __restrict__ X2, const int* __restrict__ flagp)
{
    const int isf = *flagp;
    const int tid = threadIdx.x;
    const int lane = tid & 63, wv = tid >> 6, q = lane >> 4, l15 = lane & 15;
    const int nc = blockIdx.x;
    const int g  = blockIdx.y;

    __shared__ __align__(16) char smem[53136];   // <= 54613 -> 3 blocks/CU
    bf16 (*As)[136] = (bf16(*)[136])smem;              // 34816 B
    bf16 (*Bs)[136] = (bf16(*)[136])(smem + 34816);    // 17408 B
    float (*Cs)[68] = (float(*)[68])smem;              // aliases As after MFMA
    int*   srcs = (int*)(smem + 52224);                // src node, sorted order (512 B)
    int*   sst  = (int*)(smem + 52736);                // 34 ints (136 B)
    short* rank = (short*)(smem + 52872);              // e -> sorted pos (256 B)

    if (tid < 128) {
        int p = tid;
        int e = (int)sortedE[g * EPG + p];
        rank[e] = (short)p;
        srcs[p] = edge_index[g * EPG + e];
    }
    if (tid >= 128 && tid < 161) sst[tid - 128] = estarts[g * 33 + (tid - 128)];

    {   // stage A (original edge order): cached or recompute
        int row = tid >> 1, half = (tid & 1) * 64;
        if (Ebf) {
            const uint4* src = (const uint4*)(Ebf + (size_t)(g * EPG + row) * HE_DIM + half);
            uint4 v[8];
#pragma unroll
            for (int i = 0; i < 8; ++i) v[i] = src[i];
#pragma unroll
            for (int i = 0; i < 8; ++i) *(uint4*)(&As[row][half + 8 * i]) = v[i];
        } else {
            size_t eb = (size_t)(g * EPG + row) * 3;
            int ebi[3];
            ebi[0] = ea[eb];
            ebi[1] = 119 + ea[eb + 1];
            ebi[2] = 128 + ea[eb + 2];
#pragma unroll
            for (int seg = 0; seg < 4; ++seg) {
                float a16[16];
#pragma unroll
                for (int j = 0; j < 16; ++j) a16[j] = 0.f;
#pragma unroll
                for (int f = 0; f < 3; ++f) {
                    size_t base = (size_t)ebi[f] * HE_DIM + half + seg * 16;
                    if (isf) {
                        const float4* s = (const float4*)((const float*)etab + base);
#pragma unroll
                        for (int v = 0; v < 4; ++v) {
                            float4 t = s[v];
                            a16[v*4+0] += t.x; a16[v*4+1] += t.y;
                            a16[v*4+2] += t.z; a16[v*4+3] += t.w;
                        }
                    } else {
                        const bf16* s = (const bf16*)etab + base;
#pragma unroll
                        for (int j = 0; j < 16; ++j) a16[j] += b2f(s[j]);
                    }
                }
#pragma unroll
                for (int j = 0; j < 16; ++j) As[row][half + seg * 16 + j] = f2b(a16[j]);
            }
        }
    }
    {   // stage B^T from bWt [512][128]
        int row = tid >> 2, seg = (tid & 3) * 32;
        const bf16* src = bWt + (size_t)(nc * 64 + row) * 128 + seg;
        uint4 v0 = ((const uint4*)src)[0];
        uint4 v1 = ((const uint4*)src)[1];
        uint4 v2 = ((const uint4*)src)[2];
        uint4 v3 = ((const uint4*)src)[3];
        *(uint4*)(&Bs[row][seg +  0]) = v0;
        *(uint4*)(&Bs[row][seg +  8]) = v1;
        *(uint4*)(&Bs[row][seg + 16]) = v2;
        *(uint4*)(&Bs[row][seg + 24]) = v3;
    }
    __syncthreads();

    floatx4 acc[2][4];
#pragma unroll
    for (int i = 0; i < 2; ++i)
#pragma unroll
        for (int jj = 0; jj < 4; ++jj) acc[i][jj] = (floatx4){0.f,0.f,0.f,0.f};
    const int m0 = wv * 32;
#pragma unroll
    for (int kk = 0; kk < 4; ++kk) {
        int k0 = kk * 32;
        short8 a0 = *(const short8*)(&As[m0 + l15][k0 + q * 8]);
        short8 a1 = *(const short8*)(&As[m0 + 16 + l15][k0 + q * 8]);
#pragma unroll
        for (int nt = 0; nt < 4; ++nt) {
            short8 bfr = *(const short8*)(&Bs[nt * 16 + l15][k0 + q * 8]);
            acc[0][nt] = mfma16(a0, bfr, acc[0][nt]);
            acc[1][nt] = mfma16(a1, bfr, acc[1][nt]);
        }
    }
    __syncthreads();   // MFMA LDS reads done; Cs may overwrite As
    {   // epilogue: scatter C rows into SORTED order via rank
#pragma unroll
        for (int mt = 0; mt < 2; ++mt)
#pragma unroll
            for (int r = 0; r < 4; ++r) {
                int row = m0 + mt * 16 + q * 4 + r;
                int rp = (int)rank[row];
#pragma unroll
                for (int nt = 0; nt < 4; ++nt)
                    Cs[rp][nt * 16 + l15] = acc[mt][nt][r];
            }
    }
    __syncthreads();
    {   // phase A: bond-BN + relu + bn2(z)[src] gather (sorted rows; per-element)
        int j = tid & 63, pg = (tid >> 6) * 32;
        int col = nc * 64 + j;
        float sc = scale1[col], sh = shift1[col];
        float zs = zsc ? zsc[col] : 1.f, zh = zsc ? zsh[col] : 0.f;
#pragma unroll 4
        for (int p = pg; p < pg + 32; ++p) {
            float y = Cs[p][j] * sc + sh;
            y = y > 0.f ? y : 0.f;
            float zv = Z[(size_t)srcs[p] * H_DIM + col];
            if (zsc) { zv = zv * zs + zh; zv = zv > 0.f ? zv : 0.f; }
            Cs[p][j] = y + zv;
        }
    }
    __syncthreads();
    {   // phase B: contiguous segment-sum (order == increasing original e)
        int j = tid & 63, base = (tid >> 6) * 8;
        int col = nc * 64 + j;
        float zs = zsc ? zsc[col] : 1.f, zh = zsc ? zsh[col] : 0.f;
#pragma unroll
        for (int r = 0; r < 8; ++r) {
            int n = base + r;
            int s0 = sst[n], s1 = sst[n + 1];   // wave-uniform bounds
            float a = 0.f;
            for (int idx = s0; idx < s1; ++idx)
                a += Cs[idx][j];
            size_t zi = (size_t)(g * NPG + n) * H_DIM + col;
            float zv = Z[zi];
            if (zsc) { zv = zv * zs + zh; zv = zv > 0.f ? zv : 0.f; }
            X2[zi] = a + zv;
        }
    }
}

// ---- fast GEMM: C[128x128 tiles] = A[M,K] @ Bt^T, Bt pre-transposed [N][K] bf16 ----
__global__ __launch_bounds__(256, 2)
void k_gemm(const void* __restrict__ Av, int aMode,
            const float* __restrict__ bnsc, const float* __restrict__ bnsh,
            const bf16* __restrict__ Bt,
            void* __restrict__ Cv, int cMode,
            const void* __restrict__ bias, const int* __restrict__ flagp,
            int statsMode, float* __restrict__ cs, float* __restrict__ cq,
            int K, int lda, int ldc, int mStoreMin)
{
    const int tid  = threadIdx.x;
    const int lane = tid & 63;
    const int wv   = tid >> 6;
    const int q    = lane >> 4;
    const int l15  = lane & 15;
    const int wm   = wv & 1;
    const int wn   = wv >> 1;
    const int m0   = blockIdx.y * 128;
    const int n0   = blockIdx.x * 128;

    __shared__ __align__(16) bf16 As[128][40];
    __shared__ __align__(16) bf16 Bs[128][32];

    floatx4 acc[4][4];
#pragma unroll
    for (int mt = 0; mt < 4; ++mt)
#pragma unroll
        for (int nt = 0; nt < 4; ++nt) acc[mt][nt] = (floatx4){0.f,0.f,0.f,0.f};

    const int ar = tid >> 1;
    const int ak = (tid & 1) * 16;
    const bf16* BtBase = Bt + (size_t)n0 * K;
    const int cb0 = wv * 64;
    const int cb1 = (4 + wv) * 64;

    for (int k0 = 0; k0 < K; k0 += 32) {
        short av[16];
        if (aMode == 1) {
            const float* Ap = (const float*)Av + (size_t)(m0 + ar) * lda + k0 + ak;
#pragma unroll
            for (int i = 0; i < 16; i += 4) {
                float4 f = *(const float4*)(Ap + i);
                bf16 h0 = f2b(f.x), h1 = f2b(f.y), h2 = f2b(f.z), h3 = f2b(f.w);
                av[i] = *(short*)&h0; av[i+1] = *(short*)&h1;
                av[i+2] = *(short*)&h2; av[i+3] = *(short*)&h3;
            }
        } else {
            const bf16* Ap = (const bf16*)Av + (size_t)(m0 + ar) * lda + k0 + ak;
            *(uint4*)&av[0] = *(const uint4*)Ap;
            *(uint4*)&av[8] = *(const uint4*)(Ap + 8);
            if (aMode == 2) {
#pragma unroll
                for (int i = 0; i < 16; ++i) {
                    bf16 h = *(bf16*)&av[i];
                    float f = b2f(h) * bnsc[k0 + ak + i] + bnsh[k0 + ak + i];
                    f = f > 0.f ? f : 0.f;
                    bf16 o = f2b(f);
                    av[i] = *(short*)&o;
                }
            }
        }
        __syncthreads();
        {
            int c0i = cb0 + lane;
            gload_lds16(BtBase + (size_t)(c0i >> 2) * K + k0 + (c0i & 3) * 8,
                        &Bs[0][0] + (size_t)cb0 * 8);
            int c1i = cb1 + lane;
            gload_lds16(BtBase + (size_t)(c1i >> 2) * K + k0 + (c1i & 3) * 8,
                        &Bs[0][0] + (size_t)cb1 * 8);
        }
        *(uint4*)(&As[ar][ak])     = *(uint4*)&av[0];
        *(uint4*)(&As[ar][ak + 8]) = *(uint4*)&av[8];
        __syncthreads();
        short8 af[4], bfr[4];
#pragma unroll
        for (int mt = 0; mt < 4; ++mt)
            af[mt] = *(const short8*)(&As[wm * 64 + mt * 16 + l15][q * 8]);
#pragma unroll
        for (int nt = 0; nt < 4; ++nt)
            bfr[nt] = *(const short8*)(&Bs[wn * 64 + nt * 16 + l15][q * 8]);
#pragma unroll
        for (int mt = 0; mt < 4; ++mt)
#pragma unroll
            for (int nt = 0; nt < 4; ++nt)
                acc[mt][nt] = mfma16(af[mt], bfr[nt], acc[mt][nt]);
    }

    const int isf = flagp ? *flagp : 0;
    int cm = cMode;
    if (cMode == 3) cm = isf ? 2 : 1;
    float bvv[4] = {0.f, 0.f, 0.f, 0.f};
    if (bias) {
#pragma unroll
        for (int nt = 0; nt < 4; ++nt)
            bvv[nt] = ldf(bias, (size_t)n0 + wn * 64 + nt * 16 + l15, isf);
    }
    if (cm) {
#pragma unroll
        for (int mt = 0; mt < 4; ++mt)
#pragma unroll
            for (int r = 0; r < 4; ++r) {
                int row = m0 + wm * 64 + mt * 16 + q * 4 + r;
                if (row < mStoreMin) continue;
                size_t crow = (size_t)(row - mStoreMin) * ldc + n0;
                if (cm == 2) {
                    float* Crow = (float*)Cv + crow;
#pragma unroll
                    for (int nt = 0; nt < 4; ++nt)
                        Crow[wn * 64 + nt * 16 + l15] = acc[mt][nt][r] + bvv[nt];
                } else {
                    bf16* Crow = (bf16*)Cv + crow;
#pragma unroll
                    for (int nt = 0; nt < 4; ++nt)
                        Crow[wn * 64 + nt * 16 + l15] = f2b(acc[mt][nt][r] + bvv[nt]);
                }
            }
    }
    if (statsMode) {
        float ls[4], lq[4];
#pragma unroll
        for (int nt = 0; nt < 4; ++nt) { ls[nt] = 0.f; lq[nt] = 0.f; }
#pragma unroll
        for (int nt = 0; nt < 4; ++nt)
#pragma unroll
            for (int mt = 0; mt < 4; ++mt)
#pragma unroll
                for (int r = 0; r < 4; ++r) {
                    float v = acc[mt][nt][r];
                    if (statsMode == 1) v = b2f(f2b(v));
                    ls[nt] += v; lq[nt] += v * v;
                }
        float* red = (float*)&As[0][0];
        __syncthreads();
        red[tid] = 0.f;
        __syncthreads();
#pragma unroll
        for (int nt = 0; nt < 4; ++nt) {
            int col = wn * 64 + nt * 16 + l15;
            atomicAdd(&red[col * 2],     ls[nt]);
            atomicAdd(&red[col * 2 + 1], lq[nt]);
        }
        __syncthreads();
        if (tid < 128) {
            atomicAdd(&cs[n0 + tid], red[tid * 2]);
            atomicAdd(&cq[n0 + tid], red[tid * 2 + 1]);
        }
    }
}

__global__ __launch_bounds__(256)
void k_bn_finalize(const float* __restrict__ cs, const float* __restrict__ cq,
                   const void* __restrict__ g, const void* __restrict__ be, size_t goff,
                   int cols, float invR, float* __restrict__ scale, float* __restrict__ shift,
                   const int* __restrict__ flagp)
{
    const int isf = *flagp;
    int c = blockIdx.x * 256 + threadIdx.x;
    if (c < cols) {
        float mean = cs[c] * invR;
        float var = cq[c] * invR - mean * mean;
        var = var < 0.f ? 0.f : var;
        float rstd = rsqrtf(var + 1e-5f);
        float sc = ldf(g, goff + c, isf) * rstd;
        scale[c] = sc;
        shift[c] = ldf(be, goff + c, isf) - mean * sc;
    }
}

__global__ __launch_bounds__(256)
void k_bn_apply_relu_f32(float* __restrict__ X, const float* __restrict__ scale,
                         const float* __restrict__ shift, int colmask, unsigned int nvec4)
{
    unsigned int i = blockIdx.x * 256 + threadIdx.x;
    if (i >= nvec4) return;
    float4* p = (float4*)X + i;
    int cbase = (int)(((size_t)i * 4) & (size_t)colmask);
    float4 v = *p;
    float f;
    f = v.x * scale[cbase+0] + shift[cbase+0]; v.x = f > 0.f ? f : 0.f;
    f = v.y * scale[cbase+1] + shift[cbase+1]; v.y = f > 0.f ? f : 0.f;
    f = v.z * scale[cbase+2] + shift[cbase+2]; v.z = f > 0.f ? f : 0.f;
    f = v.w * scale[cbase+3] + shift[cbase+3]; v.w = f > 0.f ? f : 0.f;
    *p = v;
}

// ---------------- attention tail ----------------
__global__ __launch_bounds__(256)
void k_att_v(const void* __restrict__ gapW, const void* __restrict__ gapB,
             const void* __restrict__ attW, const void* __restrict__ attB,
             float* __restrict__ v, const int* __restrict__ flagp)
{
    const int isf = *flagp;
    const int lane = threadIdx.x & 63, wv = threadIdx.x >> 6;
    if (blockIdx.x == 256) {
        if (wv == 0) {
            float s = 0.f;
            for (int k = lane; k < 512; k += 64) s += ldf(gapB, k, isf) * ldf(attW, k, isf);
            for (int off = 32; off > 0; off >>= 1) s += __shfl_down(s, off, 64);
            if (lane == 0) v[1024] = s + ldf(attB, 0, isf);
        }
        return;
    }
    const int o = blockIdx.x * 4 + wv;
    float s = 0.f;
    for (int k = lane; k < 512; k += 64) s += ldf(gapW, (size_t)o * 512 + k, isf) * ldf(attW, k, isf);
    for (int off = 32; off > 0; off >>= 1) s += __shfl_down(s, off, 64);
    if (lane == 0) v[o] = s;
}

__global__ __launch_bounds__(256)
void k_qv(const void* __restrict__ outW, const void* __restrict__ outB,
          const float* __restrict__ v, float* __restrict__ qv, const int* __restrict__ flagp)
{
    const int isf = *flagp;
    const int lane = threadIdx.x & 63, wv = threadIdx.x >> 6;
    if (blockIdx.x == 128) {
        if (wv == 0) {
            float s = 0.f;
            for (int o = lane; o < 1024; o += 64) s += ldf(outB, o, isf) * v[o];
            for (int off = 32; off > 0; off >>= 1) s += __shfl_down(s, off, 64);
            if (lane == 0) qv[512] = s + v[1024];
        }
        return;
    }
    const int k = blockIdx.x * 4 + wv;
    float s = 0.f;
    for (int o = lane; o < 1024; o += 64) s += ldf(outW, (size_t)k * 1024 + o, isf) * v[o];
    for (int off = 32; off > 0; off >>= 1) s += __shfl_down(s, off, 64);
    if (lane == 0) qv[k] = s;
}

__global__ __launch_bounds__(256)
void k_att_dot(const float* __restrict__ Z, const float* __restrict__ qv, float* __restrict__ att)
{
    const int lane = threadIdx.x & 63, wv = threadIdx.x >> 6;
    const int row = blockIdx.x * 4 + wv;
    const float* p = Z + (size_t)row * 512 + lane * 8;
    float s = 0.f;
#pragma unroll
    for (int i = 0; i < 8; ++i) s += p[i] * qv[lane * 8 + i];
    for (int off = 32; off > 0; off >>= 1) s += __shfl_down(s, off, 64);
    if (lane == 0) att[row] = s + qv[512];
}

__global__ __launch_bounds__(256)
void k_softmax_pool(const float* __restrict__ Z, const float* __restrict__ att, bf16* __restrict__ ZG)
{
    const int g = blockIdx.x, t = threadIdx.x;
    __shared__ float alpha[32];
    if (t < 32) alpha[t] = att[g * 32 + t];
    __syncthreads();
    if (t == 0) {
        float mx = alpha[0];
        for (int p = 1; p < 32; ++p) mx = fmaxf(mx, alpha[p]);
        float sum = 0.f;
        for (int p = 0; p < 32; ++p) { float e = __expf(alpha[p] - mx); alpha[p] = e; sum += e; }
        float inv = 1.f / sum;
        for (int p = 0; p < 32; ++p) alpha[p] *= inv;
    }
    __syncthreads();
#pragma unroll
    for (int ci = 0; ci < 2; ++ci) {
        int c = t + ci * 256;
        float acc = 0.f;
        for (int p = 0; p < 32; ++p)
            acc += alpha[p] * Z[(size_t)(g * 32 + p) * 512 + c];
        ZG[(size_t)g * 512 + c] = f2b(acc);
    }
}

// ---------------- launcher ----------------
extern "C" void kernel_launch(void* const* d_in, const int* in_sizes, int n_in,
                              void* d_out, int out_size, void* d_ws, size_t ws_size,
                              hipStream_t stream)
{
    (void)in_sizes; (void)n_in; (void)out_size;
    const int*  x          = (const int*)d_in[0];
    const int*  edge_attr  = (const int*)d_in[1];
    const int*  edge_index = (const int*)d_in[2];
    const void* node_tab   = d_in[4];
    const void* edge_tab   = d_in[5];
    const void* bondW      = d_in[6];
    const void* bondG      = d_in[8];
    const void* bondBeta   = d_in[9];
    const void* atomW1     = d_in[10];
    const void* atomG      = d_in[12];
    const void* atomBeta   = d_in[13];
    const void* atomW2     = d_in[14];
    const void* normG      = d_in[16];
    const void* normB      = d_in[17];
    const void* outW       = d_in[18];
    const void* outB       = d_in[19];
    const void* gapW       = d_in[20];
    const void* gapB       = d_in[21];
    const void* attW       = d_in[22];
    const void* attB       = d_in[23];
    const void* projW      = d_in[24];
    const void* projB      = d_in[25];

    char* ws = (char*)d_ws;
    float* z      = (float*)ws;                              // 64 MB
    bf16*  Uc     = (bf16*)(ws + 67108864ull);               // 16 MB
    bf16*  zg     = Uc;
    bf16*  hg     = (bf16*)(ws + 67108864ull + 1048576ull);
    bf16*  projWt = (bf16*)(ws + 67108864ull + 4194304ull);
    bf16*  W1t    = (bf16*)(ws + 83886080ull);               // 1 MB
    bf16*  W2t    = (bf16*)(ws + 84934656ull);               // 1 MB
    bf16*  bWt    = (bf16*)(ws + 85983232ull);               // 128 KB
    bf16*  outWt  = W1t;
    char*  st  = ws + 86114304ull;
    int*   flag = (int*)(st);
    float* S    = (float*)(st + 256);
    float* mu   = (float*)(st + 65792);
    float* cs   = (float*)(st + 66304);
    float* cq   = (float*)(st + 70400);
    float* cs2  = (float*)(st + 74496);
    float* cq2  = (float*)(st + 76544);
    float* sc1  = (float*)(st + 78592);
    float* sh1  = (float*)(st + 82688);
    float* sc2  = (float*)(st + 86784);
    float* sh2  = (float*)(st + 88832);
    float* vv   = (float*)(st + 90880);
    float* qv   = (float*)(st + 95232);
    float* att  = (float*)(st + 97536);
    short* sortedE = (short*)(st + 228608);
    int*   estarts = (int*)(st + 490752);   // base end: ws + 86,740,224
    // optional edge-embedding cache (32 MB) — only if workspace is large enough
    bf16*  Ebf = nullptr;
    if (ws_size >= 120295424ull) Ebf = (bf16*)(ws + 86740992ull);

    k_detect<<<1, 256, 0, stream>>>((const unsigned short*)node_tab, 4096, flag);
    k_edge_sort<<<N_GRAPH, 64, 0, stream>>>(edge_index, sortedE, estarts);
    hipMemsetAsync(st + 256, 0, 66048, stream);   // S + mu
    k_bond_gram<<<256, 256, 0, stream>>>(edge_attr, edge_tab, S, mu, flag);
    k_node_embed<<<N_NODES, 512, 0, stream>>>(x, node_tab, z, flag);
    if (Ebf) k_edge_embed<<<N_EDGES / 4, 512, 0, stream>>>(edge_attr, edge_tab, Ebf, flag);

    for (int l = 0; l < N_LAYERS; ++l) {
        const float* zscp = (l == 0) ? nullptr : sc2;
        const float* zshp = (l == 0) ? nullptr : sh2;

        k_transpose<<<dim3(16, 8), 256, 0, stream>>>(atomW1, (size_t)l * 512 * 1024, W1t, 512, 1024, flag);
        k_transpose<<<dim3(8, 16), 256, 0, stream>>>(atomW2, (size_t)l * 1024 * 512, W2t, 1024, 512, flag);
        k_transpose<<<dim3(8, 2), 256, 0, stream>>>(bondW, (size_t)l * 128 * 512, bWt, 128, 512, flag);

        k_bond_fold<<<512, 128, 0, stream>>>(S, mu, bWt, bondG, bondBeta, (size_t)l * 512, sc1, sh1, flag);
        k_bond_gemm_agg<<<dim3(8, N_GRAPH), 256, 0, stream>>>(edge_attr, edge_tab, Ebf, bWt,
                                                              edge_index, sortedE, estarts,
                                                              z, sc1, sh1, zscp, zshp, z, flag);

        hipMemsetAsync(cs, 0, 12288, stream);  // cs, cq, cs2, cq2
        k_gemm<<<dim3(8, 256), 256, 0, stream>>>(z, 1, nullptr, nullptr, W1t,
                                                 Uc, 1, nullptr, nullptr,
                                                 1, cs, cq, 512, 512, 1024, 24576);
        k_bn_finalize<<<4, 256, 0, stream>>>(cs, cq, atomG, atomBeta, (size_t)l * 1024,
                                             1024, 1.f / 32768.f, sc1, sh1, flag);
        for (int mi = 0; mi < 4; ++mi) {
            int mc = (mi + 3) & 3;
            float* zc = z + (size_t)mc * MC_ROWS * 512;
            if (mc != 3)
                k_gemm<<<dim3(8, 64), 256, 0, stream>>>(zc, 1, nullptr, nullptr, W1t,
                                                        Uc, 1, nullptr, nullptr,
                                                        0, nullptr, nullptr, 512, 512, 1024, 0);
            k_gemm<<<dim3(4, 64), 256, 0, stream>>>(Uc, 2, sc1, sh1, W2t,
                                                    zc, 2, nullptr, nullptr,
                                                    2, cs2, cq2, 1024, 1024, 512, 0);
        }
        k_bn_finalize<<<2, 256, 0, stream>>>(cs2, cq2, normG, normB, (size_t)l * 512,
                                             512, 1.f / 32768.f, sc2, sh2, flag);
    }
    k_bn_apply_relu_f32<<<16384, 256, 0, stream>>>(z, sc2, sh2, 511, 4194304u);

    k_att_v<<<257, 256, 0, stream>>>(gapW, gapB, attW, attB, vv, flag);
    k_qv<<<129, 256, 0, stream>>>(outW, outB, vv, qv, flag);
    k_att_dot<<<8192, 256, 0, stream>>>(z, qv, att);
    k_softmax_pool<<<N_GRAPH, 256, 0, stream>>>(z, att, zg);
    k_transpose<<<dim3(16, 8), 256, 0, stream>>>(outW, 0, outWt, 512, 1024, flag);
    k_gemm<<<dim3(8, 8), 256, 0, stream>>>(zg, 0, nullptr, nullptr, outWt,
                                           hg, 1, outB, flag,
                                           0, nullptr, nullptr, 512, 512, 1024, 0);
    k_transpose<<<dim3(16, 16), 256, 0, stream>>>(projW, 0, projWt, 1024, 1024, flag);
    k_gemm<<<dim3(8, 8), 256, 0, stream>>>(hg, 0, nullptr, nullptr, projWt,
                                           d_out, 3, projB, flag,
                                           0, nullptr, nullptr, 1024, 1024, 1024, 0);
}